// Round 16
// baseline (1196.659 us; speedup 1.0000x reference)
//
#include <hip/hip_runtime.h>
#include <math.h>

#define TT 1024
#define NB 128

typedef float f32x4 __attribute__((ext_vector_type(4)));
typedef __bf16 bf16x8 __attribute__((ext_vector_type(8)));

__device__ __forceinline__ float4 ld4(const float* p){ return *(const float4*)p; }
__device__ __forceinline__ float rdlane(float v, int lane){
  return __int_as_float(__builtin_amdgcn_readlane(__float_as_int(v), lane));
}
__device__ __forceinline__ unsigned short bf16rne(float x){
  unsigned u = __float_as_uint(x);
  return (unsigned short)((u + 0x7FFF + ((u >> 16) & 1)) >> 16);
}

// ================= bf16 MFMA GEMM: C = epi(A @ B^T_panels), 64x128 tile =================
template<int EPI, int OUTBF>
__global__ __launch_bounds__(256)
void mgemm_k(const unsigned short* __restrict__ A, const unsigned short* __restrict__ B,
             void* __restrict__ Cv, int K, int lda, int ldb, int ldc,
             long sA, long sB, long sC,
             const float* __restrict__ bias,
             const float* __restrict__ e1, long sE1, const float* __restrict__ e2)
{
  const int bz = blockIdx.z;
  A += (long)bz * sA; B += (long)bz * sB;
  __shared__ char lds[12288];
  char* As = lds;
  char* Bs = lds + 4096;
  const int tid = threadIdx.x;
  const int l = tid & 63, wid = tid >> 6;
  const int wr = wid >> 1, wc = wid & 1;
  const int m0 = blockIdx.y * 64, n0 = blockIdx.x * 128;
  const int lrow = l & 15, lslot = (l >> 4) << 4;
  f32x4 acc[2][4] = {};

  for (int kk = 0; kk < K; kk += 32) {
    {
      int row = tid >> 2, c16 = (tid & 3) << 4;
      int sw = c16 ^ (((row >> 1) & 3) << 4);
      uint4 va = *(const uint4*)(A + (long)(m0 + row) * lda + kk + (c16 >> 1));
      *(uint4*)(As + row * 64 + sw) = va;
    }
#pragma unroll
    for (int i = 0; i < 2; ++i) {
      int idx = i * 256 + tid;
      int row = idx >> 2, c16 = (idx & 3) << 4;
      int sw = c16 ^ (((row >> 1) & 3) << 4);
      uint4 vb = *(const uint4*)(B + (long)(n0 + row) * ldb + kk + (c16 >> 1));
      *(uint4*)(Bs + row * 64 + sw) = vb;
    }
    __syncthreads();
    bf16x8 af[2], bfr[4];
#pragma unroll
    for (int t = 0; t < 2; ++t) {
      int ra = wr * 32 + t * 16 + lrow;
      af[t]  = *(const bf16x8*)(As + ra * 64 + (lslot ^ (((ra >> 1) & 3) << 4)));
    }
#pragma unroll
    for (int t = 0; t < 4; ++t) {
      int rb = wc * 64 + t * 16 + lrow;
      bfr[t] = *(const bf16x8*)(Bs + rb * 64 + (lslot ^ (((rb >> 1) & 3) << 4)));
    }
#pragma unroll
    for (int mi = 0; mi < 2; ++mi)
#pragma unroll
      for (int ni = 0; ni < 4; ++ni)
        acc[mi][ni] = __builtin_amdgcn_mfma_f32_16x16x32_bf16(af[mi], bfr[ni], acc[mi][ni], 0, 0, 0);
    __syncthreads();
  }

  float* Cf = (float*)Cv; unsigned short* Cb = (unsigned short*)Cv;
  if (OUTBF) Cb += (long)bz * sC; else Cf += (long)bz * sC;
  if (e1) e1 += (long)bz * sE1;
#pragma unroll
  for (int mi = 0; mi < 2; ++mi)
#pragma unroll
  for (int ni = 0; ni < 4; ++ni)
#pragma unroll
  for (int r = 0; r < 4; ++r) {
    int m = m0 + wr * 32 + mi * 16 + ((l >> 4) << 2) + r;
    int n = n0 + wc * 64 + ni * 16 + (l & 15);
    float v = acc[mi][ni][r];
    if (EPI == 1) v = tanhf(v + bias[n]);
    else if (EPI == 2) v = (m == n) ? 0.f : expf(tanhf(v));
    else if (EPI == 3) v = fmaxf(v + bias[n], 0.f);
    else if (EPI == 4) v = v + e1[m] * e2[n];
    if (OUTBF) Cb[(long)m * ldc + n] = bf16rne(v);
    else       Cf[(long)m * ldc + n] = v;
  }
}

// ========== dual-output variant for pinp / cinp, 64x128 tile, bf16 out ==========
__global__ __launch_bounds__(256)
void mgemm_pc_k(const unsigned short* __restrict__ A1, const unsigned short* __restrict__ A2,
                const unsigned short* __restrict__ B,
                unsigned short* __restrict__ C1, unsigned short* __restrict__ C2,
                int K, int lda, int ldb, int ldc, long sA, long sB, long sC,
                const float* __restrict__ e1, long sE1, const float* __restrict__ e2)
{
  const int z = blockIdx.z;
  const int bz = z & 7;
  const bool second = (z >= 8);
  const unsigned short* A = (second ? A2 : A1) + (long)bz * sA;
  const unsigned short* Bp = B + (long)bz * sB;
  unsigned short* C = (second ? C2 : C1) + (long)bz * sC;
  const float* e1p = second ? nullptr : (e1 + (long)bz * sE1);
  __shared__ char lds[12288];
  char* As = lds; char* Bs = lds + 4096;
  const int tid = threadIdx.x;
  const int l = tid & 63, wid = tid >> 6;
  const int wr = wid >> 1, wc = wid & 1;
  const int m0 = blockIdx.y * 64, n0 = blockIdx.x * 128;
  const int lrow = l & 15, lslot = (l >> 4) << 4;
  f32x4 acc[2][4] = {};
  for (int kk = 0; kk < K; kk += 32) {
    {
      int row = tid >> 2, c16 = (tid & 3) << 4;
      int sw = c16 ^ (((row >> 1) & 3) << 4);
      uint4 va = *(const uint4*)(A + (long)(m0 + row) * lda + kk + (c16 >> 1));
      *(uint4*)(As + row * 64 + sw) = va;
    }
#pragma unroll
    for (int i = 0; i < 2; ++i) {
      int idx = i * 256 + tid;
      int row = idx >> 2, c16 = (idx & 3) << 4;
      int sw = c16 ^ (((row >> 1) & 3) << 4);
      uint4 vb = *(const uint4*)(Bp + (long)(n0 + row) * ldb + kk + (c16 >> 1));
      *(uint4*)(Bs + row * 64 + sw) = vb;
    }
    __syncthreads();
    bf16x8 af[2], bfr[4];
#pragma unroll
    for (int t = 0; t < 2; ++t) {
      int ra = wr * 32 + t * 16 + lrow;
      af[t]  = *(const bf16x8*)(As + ra * 64 + (lslot ^ (((ra >> 1) & 3) << 4)));
    }
#pragma unroll
    for (int t = 0; t < 4; ++t) {
      int rb = wc * 64 + t * 16 + lrow;
      bfr[t] = *(const bf16x8*)(Bs + rb * 64 + (lslot ^ (((rb >> 1) & 3) << 4)));
    }
#pragma unroll
    for (int mi = 0; mi < 2; ++mi)
#pragma unroll
      for (int ni = 0; ni < 4; ++ni)
        acc[mi][ni] = __builtin_amdgcn_mfma_f32_16x16x32_bf16(af[mi], bfr[ni], acc[mi][ni], 0, 0, 0);
    __syncthreads();
  }
#pragma unroll
  for (int mi = 0; mi < 2; ++mi)
#pragma unroll
  for (int ni = 0; ni < 4; ++ni)
#pragma unroll
  for (int r = 0; r < 4; ++r) {
    int m = m0 + wr * 32 + mi * 16 + ((l >> 4) << 2) + r;
    int n = n0 + wc * 64 + ni * 16 + (l & 15);
    float v = acc[mi][ni][r];
    if (e1p) v = v + e1p[m] * e2[n];
    C[(long)m * ldc + n] = bf16rne(v);
  }
}

// ---------------- feature split (+ strb bf16 emit) ----------------
__global__ void split_k(const float* __restrict__ in, float* __restrict__ sem,
                        float* __restrict__ str, unsigned short* __restrict__ strb){
  long row = blockIdx.x;
  int c = threadIdx.x << 2;
  float4 v = ld4(in + row * 1024 + c);
  bool isStr = (c >= 256 && c < 512) || (c >= 768);
  int off;
  float* dst;
  if (c < 256)      { dst = sem + row * 512 + c;               off = c; }
  else if (c < 512) { dst = str + row * 512 + (c - 256);       off = c - 256; }
  else if (c < 768) { dst = sem + row * 512 + 256 + (c - 512); off = 0; }
  else              { dst = str + row * 512 + 256 + (c - 768); off = 256 + (c - 768); }
  *(float4*)dst = v;
  if (isStr) {
    unsigned lo = bf16rne(v.x) | ((unsigned)bf16rne(v.y) << 16);
    unsigned hi = bf16rne(v.z) | ((unsigned)bf16rne(v.w) << 16);
    uint2 w; w.x = lo; w.y = hi;
    *(uint2*)(strb + row * 512 + off) = w;
  }
}

// ---------------- fused 3-weight cast ----------------
__global__ void castw3_k(const float* __restrict__ Wtp, const float* __restrict__ Wtc,
                         const float* __restrict__ Wfz,
                         unsigned short* __restrict__ wtpb, unsigned short* __restrict__ wtcb,
                         unsigned short* __restrict__ wfzb){
  long i = ((long)blockIdx.x * 256 + threadIdx.x) << 2;
  const float* src; unsigned short* dst; long off;
  if (i < 262144)      { src = Wtp; dst = wtpb; off = i; }
  else if (i < 524288) { src = Wtc; dst = wtcb; off = i - 262144; }
  else                 { src = Wfz; dst = wfzb; off = i - 524288; }
  float4 v = ld4(src + off);
  unsigned lo = bf16rne(v.x) | ((unsigned)bf16rne(v.y) << 16);
  unsigned hi = bf16rne(v.z) | ((unsigned)bf16rne(v.w) << 16);
  uint2 w; w.x = lo; w.y = hi;
  *(uint2*)(dst + off) = w;
}

__global__ __launch_bounds__(256) void castT_k(const float* __restrict__ src, unsigned short* __restrict__ dst,
                                               int R, int C, long sS, long sD){
  int b = blockIdx.z;
  src += (long)b * sS; dst += (long)b * sD;
  __shared__ float t[32][33];
  int r0 = blockIdx.y * 32, c0 = blockIdx.x * 32;
  int tx = threadIdx.x & 31, ty = threadIdx.x >> 5;
#pragma unroll
  for (int j = 0; j < 32; j += 8)
    t[ty + j][tx] = src[(long)(r0 + ty + j) * C + c0 + tx];
  __syncthreads();
#pragma unroll
  for (int j = 0; j < 32; j += 8)
    dst[(long)(c0 + ty + j) * R + r0 + tx] = bf16rne(t[tx][ty + j]);
}

__global__ void semcopy_k(const float* __restrict__ sem, unsigned short* __restrict__ finpb){
  long idx = ((long)blockIdx.x * 256 + threadIdx.x) << 2;
  long row = idx >> 9; int col = (int)(idx & 511);
  float4 v = ld4(sem + idx);
  unsigned lo = bf16rne(v.x) | ((unsigned)bf16rne(v.y) << 16);
  unsigned hi = bf16rne(v.z) | ((unsigned)bf16rne(v.w) << 16);
  uint2 w; w.x = lo; w.y = hi;
  *(uint2*)(finpb + row * 1536 + col) = w;
}

// ---------------- f_i = exp(tanh(str . wfi)) ----------------
__global__ void fi_k(const float* __restrict__ str, const float* __restrict__ wfi, float* __restrict__ fi){
  int row = blockIdx.x * 4 + (threadIdx.x >> 6);
  int lane = threadIdx.x & 63;
  const float* p = str + (long)row * 512;
  float acc = 0.f;
  for (int c = lane; c < 512; c += 64) acc = fmaf(p[c], wfi[c], acc);
  for (int off = 32; off; off >>= 1) acc += __shfl_down(acc, off, 64);
  if (lane == 0) fi[row] = expf(tanhf(acc));
}

// ---------------- column sums (8 row-chunk partials) ----------------
__global__ void colsum_k(const float* __restrict__ A, float* __restrict__ csp){
  int b = blockIdx.y, rc = blockIdx.z;
  int j = blockIdx.x * 256 + threadIdx.x;
  const float* p = A + (long)b * TT * TT + (long)rc * 128 * TT + j;
  float acc = 0.f;
  for (int i = 0; i < 128; ++i) acc += p[(long)i * TT];
  csp[rc * 8192 + b * TT + j] = acc;
}

// ---------------- build L_bar (+ emit Cold0 hi/lo, 128 cols) ----------------
__global__ void buildw_k(const float* __restrict__ A, const float* __restrict__ fi,
                         const float* __restrict__ csp, float* __restrict__ W,
                         unsigned short* __restrict__ Ch0, unsigned short* __restrict__ Cl0){
  long idx = (long)blockIdx.x * 256 + threadIdx.x;
  long b = idx >> 20;
  long r = idx & 1048575;
  int i = (int)(r >> 10), j = (int)(r & 1023);
  float v;
  if (i == 0)      v = fi[b * TT + j];
  else if (i == j) {
    v = 0.f;
#pragma unroll
    for (int c = 0; c < 8; ++c) v += csp[c * 8192 + b * TT + j];
  }
  else             v = -A[idx];
  W[idx] = v;
  if (j < 128) {
    unsigned short h = bf16rne(v);
    float hf = __uint_as_float((unsigned)h << 16);
    Ch0[b * 131072 + i * 128 + j] = h;
    Cl0[b * 131072 + i * 128 + j] = bf16rne(v - hf);
  }
}

// ---------------- GJ fused: {two-level 128x128 diag inverse in LDS} + {Rnew 64-col chunk} ----------------
// grid (8 batches-x, 16 J-chunks-y), 256 thr, ~109 KB LDS (1 block/CU, 128 concurrent blocks).
#define G16C(c) { float bc = rdlane(e[(c)], K16_);               \
                  float z  = piv ? 0.f : e[(c)];                 \
                  e[(c)] = fmaf(-t, bc, z); }
#define G16S(k) { enum { K16_ = (k) };                           \
    float pk = rdlane(e[K16_], K16_);                            \
    float pr = 1.f / pk;                                         \
    float f  = e[K16_];                                          \
    bool piv = (mm == K16_);                                     \
    float t  = piv ? -pr : f * pr;                               \
    G16C(0) G16C(1) G16C(2) G16C(3) G16C(4) G16C(5) G16C(6) G16C(7) \
    G16C(8) G16C(9) G16C(10) G16C(11) G16C(12) G16C(13) G16C(14) G16C(15) \
    e[K16_] = -t; }

__global__ __launch_bounds__(256) void gj_fprep3_k(const float* __restrict__ W,
                                                   float* __restrict__ Rnew,
                                                   unsigned short* __restrict__ RTh, unsigned short* __restrict__ RTl,
                                                   int k0){
  __shared__ float P[128][129];
  __shared__ float Rt[16][132];
  __shared__ float S[128][68];
  int b = blockIdx.x;
  int J = blockIdx.y * 64;
  int tid = threadIdx.x;
  int l = tid & 63;
  int r2 = tid & 127, hh = tid >> 7;
  int mm = l & 15;
  int g = tid >> 4;                    // 0..15
  // stage W rows [k0,k0+128) x cols [J,J+64)
  const float* Wr = W + (long)b * 1048576 + (long)k0 * 1024 + J;
  for (int i = tid; i < 2048; i += 256) {
    int q = i >> 4, j4 = (i & 15) << 2;
    *(float4*)&S[q][j4] = ld4(Wr + (long)q * 1024 + j4);
  }
  // load 128x128 diag block
  const float* Wd = W + (long)b * 1048576 + (long)(k0 + r2) * 1024 + k0 + hh * 64;
#pragma unroll
  for (int c = 0; c < 64; c += 4) {
    float4 v = ld4(Wd + c);
    P[r2][hh * 64 + c]     = v.x; P[r2][hh * 64 + c + 1] = v.y;
    P[r2][hh * 64 + c + 2] = v.z; P[r2][hh * 64 + c + 3] = v.w;
  }
  __syncthreads();
  // two-level GJ: 8 sub-blocks x {16x16 reg GJ + rank-16 update over 128 cols}
  for (int kb = 0; kb < 8; ++kb) {
    int kbase = kb << 4;
    float e[16];
#pragma unroll
    for (int c = 0; c < 16; ++c) e[c] = P[kbase + mm][kbase + c];
    G16S(0) G16S(1) G16S(2) G16S(3) G16S(4) G16S(5) G16S(6) G16S(7)
    G16S(8) G16S(9) G16S(10) G16S(11) G16S(12) G16S(13) G16S(14) G16S(15)
    float Cc[16];
#pragma unroll
    for (int c = 0; c < 16; ++c) Cc[c] = P[r2][kbase + c];
    // Rt[mm][g*8 .. g*8+8)
    {
      int col0 = g << 3;
      float rr[8];
      if (g == (kb << 1)) {
#pragma unroll
        for (int cc = 0; cc < 8; ++cc) rr[cc] = e[cc];
      } else if (g == (kb << 1) + 1) {
#pragma unroll
        for (int cc = 0; cc < 8; ++cc) rr[cc] = e[8 + cc];
      } else {
#pragma unroll
        for (int cc = 0; cc < 8; ++cc) rr[cc] = 0.f;
#pragma unroll
        for (int j = 0; j < 16; ++j) {
          float ej = e[j];
#pragma unroll
          for (int cc = 0; cc < 8; ++cc)
            rr[cc] = fmaf(ej, P[kbase + j][col0 + cc], rr[cc]);
        }
      }
#pragma unroll
      for (int cc = 0; cc < 8; ++cc) Rt[mm][col0 + cc] = rr[cc];
    }
    __syncthreads();
    // row updates (thread owns 64 cols: hh*64 .. hh*64+64)
    if (r2 >= kbase && r2 < kbase + 16) {
#pragma unroll
      for (int c = 0; c < 64; c += 4) {
        float4 v = *(float4*)&Rt[r2 - kbase][hh * 64 + c];
        P[r2][hh * 64 + c]     = v.x; P[r2][hh * 64 + c + 1] = v.y;
        P[r2][hh * 64 + c + 2] = v.z; P[r2][hh * 64 + c + 3] = v.w;
      }
    } else {
#pragma unroll
      for (int cb = 0; cb < 4; ++cb) {
        int cbase = hh * 64 + (cb << 4);
        float acc[16];
#pragma unroll
        for (int c = 0; c < 16; ++c) {
          int cg = cbase + c;
          bool inK = (cg >= kbase && cg < kbase + 16);
          acc[c] = inK ? 0.f : P[r2][cg];
        }
#pragma unroll
        for (int j = 0; j < 16; ++j) {
          float cj = Cc[j];
          float4 v0 = *(float4*)&Rt[j][cbase + 0];
          float4 v1 = *(float4*)&Rt[j][cbase + 4];
          float4 v2 = *(float4*)&Rt[j][cbase + 8];
          float4 v3 = *(float4*)&Rt[j][cbase + 12];
          acc[0]  = fmaf(-cj, v0.x, acc[0]);  acc[1]  = fmaf(-cj, v0.y, acc[1]);
          acc[2]  = fmaf(-cj, v0.z, acc[2]);  acc[3]  = fmaf(-cj, v0.w, acc[3]);
          acc[4]  = fmaf(-cj, v1.x, acc[4]);  acc[5]  = fmaf(-cj, v1.y, acc[5]);
          acc[6]  = fmaf(-cj, v1.z, acc[6]);  acc[7]  = fmaf(-cj, v1.w, acc[7]);
          acc[8]  = fmaf(-cj, v2.x, acc[8]);  acc[9]  = fmaf(-cj, v2.y, acc[9]);
          acc[10] = fmaf(-cj, v2.z, acc[10]); acc[11] = fmaf(-cj, v2.w, acc[11]);
          acc[12] = fmaf(-cj, v3.x, acc[12]); acc[13] = fmaf(-cj, v3.y, acc[13]);
          acc[14] = fmaf(-cj, v3.z, acc[14]); acc[15] = fmaf(-cj, v3.w, acc[15]);
        }
#pragma unroll
        for (int c = 0; c < 16; ++c) P[r2][cbase + c] = acc[c];
      }
    }
    __syncthreads();
  }
  // P = Dinv (128x128). R chunk: out[p][c] = sum_q Dinv[p][q] * S[q][c], thread: p=r2, cols hh*32..+32
  float a2[32] = {};
  for (int q = 0; q < 128; ++q) {
    float d = P[r2][q];
#pragma unroll
    for (int c = 0; c < 32; ++c) a2[c] = fmaf(d, S[q][hh * 32 + c], a2[c]);
  }
  __syncthreads();
#pragma unroll
  for (int c = 0; c < 32; ++c) {
    int jg = J + hh * 32 + c;
    float v = a2[c];
    if (jg >= k0 && jg < k0 + 128) v = P[r2][jg - k0];
    S[r2][hh * 32 + c] = v;
  }
  __syncthreads();
  float* Rb = Rnew + (long)b * 131072 + J;
  for (int i = tid; i < 2048; i += 256) {
    int rr2 = i >> 4, j4 = (i & 15) << 2;
    *(float4*)(Rb + (long)rr2 * 1024 + j4) = *(float4*)&S[rr2][j4];
  }
  unsigned short* th = RTh + (long)b * 131072 + (long)J * 128;
  unsigned short* tl = RTl + (long)b * 131072 + (long)J * 128;
  for (int i = tid; i < 8192; i += 256) {
    int jl = i >> 7, pp = i & 127;
    float v = S[pp][jl];
    unsigned short h = bf16rne(v);
    float hf = __uint_as_float((unsigned)h << 16);
    th[i] = h;
    tl[i] = bf16rne(v - hf);
  }
}

// ---------------- GJ trailing update: 64x64 tiles, K=128, bf16x3 MFMA ----------------
__global__ __launch_bounds__(256) void gupd_k(const unsigned short* __restrict__ Ch, const unsigned short* __restrict__ Cl,
                                              const unsigned short* __restrict__ RTh, const unsigned short* __restrict__ RTl,
                                              const float* __restrict__ Rnew, float* __restrict__ W,
                                              unsigned short* __restrict__ ChN, unsigned short* __restrict__ ClN, int k0){
  int b = blockIdx.x;
  const unsigned short* Ahp = Ch + (long)b * 131072;
  const unsigned short* Alp = Cl + (long)b * 131072;
  const unsigned short* Bhp = RTh + (long)b * 131072;
  const unsigned short* Blp = RTl + (long)b * 131072;
  const float* Rb = Rnew + (long)b * 131072;
  float* Wb = W + (long)b * 1048576;
  unsigned short* CnH = ChN + (long)b * 131072;
  unsigned short* CnL = ClN + (long)b * 131072;
  const int tid = threadIdx.x, l = tid & 63, wid = tid >> 6;
  const int wr = wid >> 1, wc = wid & 1;
  const int m0 = blockIdx.y * 64, n0 = blockIdx.z * 64;
  const int lrow = l & 15, kc8 = (l >> 4) << 3;
  f32x4 acc[2][2] = {};
#pragma unroll
  for (int kk = 0; kk < 4; ++kk) {
    bf16x8 ah[2], al4[2], bh[2], bl4[2];
#pragma unroll
    for (int t = 0; t < 2; ++t) {
      int ra = m0 + wr * 32 + t * 16 + lrow;
      long offa = (long)ra * 128 + kk * 32 + kc8;
      ah[t]  = *(const bf16x8*)(Ahp + offa);
      al4[t] = *(const bf16x8*)(Alp + offa);
      int rb = n0 + wc * 32 + t * 16 + lrow;
      long offb = (long)rb * 128 + kk * 32 + kc8;
      bh[t]  = *(const bf16x8*)(Bhp + offb);
      bl4[t] = *(const bf16x8*)(Blp + offb);
    }
#pragma unroll
    for (int mi = 0; mi < 2; ++mi)
#pragma unroll
      for (int ni = 0; ni < 2; ++ni) {
        acc[mi][ni] = __builtin_amdgcn_mfma_f32_16x16x32_bf16(ah[mi],  bh[ni],  acc[mi][ni], 0, 0, 0);
        acc[mi][ni] = __builtin_amdgcn_mfma_f32_16x16x32_bf16(ah[mi],  bl4[ni], acc[mi][ni], 0, 0, 0);
        acc[mi][ni] = __builtin_amdgcn_mfma_f32_16x16x32_bf16(al4[mi], bh[ni],  acc[mi][ni], 0, 0, 0);
      }
  }
#pragma unroll
  for (int mi = 0; mi < 2; ++mi)
#pragma unroll
  for (int ni = 0; ni < 2; ++ni)
#pragma unroll
  for (int r = 0; r < 4; ++r) {
    int m = m0 + wr * 32 + mi * 16 + ((l >> 4) << 2) + r;
    int n = n0 + wc * 32 + ni * 16 + (l & 15);
    bool rowK = (m >= k0 && m < k0 + NB);
    bool colK = (n >= k0 && n < k0 + NB);
    float v;
    if (rowK)      v = Rb[(long)(m - k0) * 1024 + n];
    else if (colK) v = -acc[mi][ni][r];
    else           v = Wb[(long)m * 1024 + n] - acc[mi][ni][r];
    Wb[(long)m * 1024 + n] = v;
    int cn = n - k0 - NB;
    if (cn >= 0 && cn < NB) {
      unsigned short h = bf16rne(v);
      float hf = __uint_as_float((unsigned)h << 16);
      CnH[(long)m * 128 + cn] = h;
      CnL[(long)m * 128 + cn] = bf16rne(v - hf);
    }
  }
}

// ---------------- d0, diag, df col 0 ----------------
__global__ void ddiag_k(const float* __restrict__ W, const float* __restrict__ fi,
                        float* __restrict__ d0, float* __restrict__ diag, float* __restrict__ dfout){
  int t = blockIdx.x * 256 + threadIdx.x;
  int b = t >> 10, i = t & 1023;
  const float* Wb = W + (long)b * TT * TT;
  float dv = fi[t] * Wb[(long)i * TT];
  d0[t] = dv;
  diag[t] = Wb[(long)i * TT + i];
  dfout[(long)b * TT * 1025 + (long)i * 1025] = dv;
}

// ---------------- dx: compute, emit bf16 dx + bf16 dx^T + df store ----------------
__global__ __launch_bounds__(256) void dx_k(const float* __restrict__ A, const float* __restrict__ W,
                                            const float* __restrict__ diag, float* __restrict__ dfout,
                                            unsigned short* __restrict__ dxb, unsigned short* __restrict__ dxTb){
  int b = blockIdx.z;
  int i0 = blockIdx.y * 64, j0 = blockIdx.x * 64;
  const float* Wb = W + (long)b * TT * TT;
  const float* Ab = A + (long)b * TT * TT;
  __shared__ float Ls[64][65];
  __shared__ float Sx[64][65];
  int tid = threadIdx.x;
  for (int idx = tid; idx < 4096; idx += 256) {
    int r = idx >> 6, c = idx & 63;
    Ls[r][c] = Wb[(long)(j0 + r) * TT + i0 + c];
  }
  __syncthreads();
  for (int idx = tid; idx < 4096; idx += 256) {
    int r = idx >> 6, c = idx & 63;
    int i = i0 + r, j = j0 + c;
    float a = Ab[(long)i * TT + j];
    float v = 0.f;
    if (j > 0) v = a * diag[b * TT + j];
    if (i > 0) v -= a * Ls[c][r];
    dxb[(long)b * 1048576 + (long)i * 1024 + j] = bf16rne(v);
    Sx[r][c] = v;
  }
  __syncthreads();
  float* dfb = dfout + (long)b * TT * 1025;
  unsigned short* dtb = dxTb + (long)b * 1048576;
  for (int idx = tid; idx < 4096; idx += 256) {
    int r = idx >> 6, c = idx & 63;
    float v = Sx[c][r];
    dfb[(long)(j0 + r) * 1025 + i0 + 1 + c] = v;
    dtb[(long)(j0 + r) * 1024 + i0 + c] = bf16rne(v);
  }
}

extern "C" void kernel_launch(void* const* d_in, const int* in_sizes, int n_in,
                              void* d_out, int out_size, void* d_ws, size_t ws_size,
                              hipStream_t stream){
  const float* input   = (const float*)d_in[0];
  const float* Wtp     = (const float*)d_in[1];
  const float* btp     = (const float*)d_in[2];
  const float* Wtc     = (const float*)d_in[3];
  const float* btc     = (const float*)d_in[4];
  const float* wfi     = (const float*)d_in[5];
  const float* Wbil    = (const float*)d_in[6];
  const float* exparam = (const float*)d_in[7];
  const float* Wfz     = (const float*)d_in[8];
  const float* bfz     = (const float*)d_in[9];

  if (ws_size < 150000000UL) return;

  float* ws   = (float*)d_ws;
  float* sem   = ws;                    // 4,194,304 f
  float* strv  = ws + 4194304;          // 4,194,304 f  [later: dxb bf16]
  float* Abuf  = ws + 8388608;          // 8,388,608 f  [later: finpb bf16]
  float* Wbuf  = ws + 16777216;         // 8,388,608 f
  unsigned short* strb = (unsigned short*)(ws + 25165824);  // dead after tp/tc mgemms
  unsigned short* tpb  = (unsigned short*)(ws + 27262976);  // dead after tpw mgemm
  unsigned short* tcb  = (unsigned short*)(ws + 29360128);  // [later: semTb]
  unsigned short* tpwb = (unsigned short*)(ws + 31457280);  // dead after A-score [later: RTh/RTl]
  unsigned short* wtpb = (unsigned short*)(ws + 33554432);
  unsigned short* wtcb = (unsigned short*)(ws + 33685504);
  unsigned short* wbilT= (unsigned short*)(ws + 33816576);
  unsigned short* wfzb = (unsigned short*)(ws + 33947648);
  float* fi    = ws + 34340864;         // 8192
  float* csp   = ws + 34349056;         // 65,536
  float* d0    = ws + 34414592;         // 8192
  float* dg    = ws + 34422784;         // 8192
  float* Rnew  = ws + 34430976;         // 1,048,576 f (8 x 128 x 1024)
  // GJ panel buffers alias dead bf16 regions:
  unsigned short* ChA = (unsigned short*)(ws + 25165824);   // 8x1024x128 bf16 (over strb)
  unsigned short* ClA = (unsigned short*)(ws + 25690112);
  unsigned short* ChB = (unsigned short*)(ws + 26214400);   // (over tpb)
  unsigned short* ClB = (unsigned short*)(ws + 26738688);
  unsigned short* RTh = (unsigned short*)(ws + 31457280);   // (over tpwb)
  unsigned short* RTl = (unsigned short*)(ws + 31981568);
  unsigned short* dxb   = (unsigned short*)strv;
  unsigned short* dxTb  = (unsigned short*)(ws + 25165824); // after GJ (Ch/Cl dead)
  unsigned short* semTb = (unsigned short*)(ws + 29360128);
  unsigned short* finpb = (unsigned short*)Abuf;

  float* outp = (float*)d_out;
  float* dfp  = outp + 4194304;

  split_k<<<8192, 256, 0, stream>>>(input, sem, strv, strb);
  castw3_k<<<1280, 256, 0, stream>>>(Wtp, Wtc, Wfz, wtpb, wtcb, wfzb);
  castT_k<<<dim3(16,16,1), 256, 0, stream>>>(Wbil, wbilT, 512, 512, 0, 0);
  fi_k<<<2048, 256, 0, stream>>>(strv, wfi, fi);
  mgemm_k<1,1><<<dim3(4,128,1),256,0,stream>>>(strb, wtpb, tpb, 512, 512, 512, 512, 0,0,0, btp, nullptr,0,nullptr);
  mgemm_k<1,1><<<dim3(4,128,1),256,0,stream>>>(strb, wtcb, tcb, 512, 512, 512, 512, 0,0,0, btc, nullptr,0,nullptr);
  mgemm_k<0,1><<<dim3(4,128,1),256,0,stream>>>(tpb, wbilT, tpwb, 512, 512, 512, 512, 0,0,0, nullptr, nullptr,0,nullptr);
  mgemm_k<2,0><<<dim3(8,16,8),256,0,stream>>>(tpwb, tcb, Abuf, 512, 512, 512, 1024, 524288,524288,1048576, nullptr, nullptr,0,nullptr);
  castT_k<<<dim3(16,32,8), 256, 0, stream>>>(sem, semTb, 1024, 512, 524288, 524288);
  colsum_k<<<dim3(4,8,8),256,0,stream>>>(Abuf, csp);
  buildw_k<<<32768,256,0,stream>>>(Abuf, fi, csp, Wbuf, ChA, ClA);
  // blocked in-place Gauss-Jordan, NB=128: {fprep3(dinv128+Rnew), gupd} x 8
  for (int s = 0; s < 8; ++s) {
    int k0 = s * NB;
    unsigned short* ChI = (s & 1) ? ChB : ChA;
    unsigned short* ClI = (s & 1) ? ClB : ClA;
    unsigned short* ChO = (s & 1) ? ChA : ChB;
    unsigned short* ClO = (s & 1) ? ClA : ClB;
    gj_fprep3_k<<<dim3(8,16),256,0,stream>>>(Wbuf, Rnew, RTh, RTl, k0);
    gupd_k<<<dim3(8,16,16),256,0,stream>>>(ChI, ClI, RTh, RTl, Rnew, Wbuf, ChO, ClO, k0);
  }
  ddiag_k<<<32,256,0,stream>>>(Wbuf, fi, d0, dg, dfp);
  dx_k<<<dim3(16,16,8),256,0,stream>>>(Abuf, Wbuf, dg, dfp, dxb, dxTb);
  semcopy_k<<<4096,256,0,stream>>>(sem, finpb);
  mgemm_pc_k<<<dim3(4,16,16),256,0,stream>>>(dxTb, dxb, semTb, finpb + 512, finpb + 1024,
                                             1024, 1024, 1024, 1536, 1048576, 524288, 1572864,
                                             d0, 1024, exparam);
  mgemm_k<3,0><<<dim3(4,128,1),256,0,stream>>>(finpb, wfzb, outp, 1536, 1536, 1536, 512, 0,0,0, bfz, nullptr,0,nullptr);
}

// Round 17
// 1024.382 us; speedup vs baseline: 1.1682x; 1.1682x over previous
//
#include <hip/hip_runtime.h>
#include <math.h>

#define TT 1024
#define NB 64

typedef float f32x4 __attribute__((ext_vector_type(4)));
typedef __bf16 bf16x8 __attribute__((ext_vector_type(8)));

__device__ __forceinline__ float4 ld4(const float* p){ return *(const float4*)p; }
__device__ __forceinline__ float rdlane(float v, int lane){
  return __int_as_float(__builtin_amdgcn_readlane(__float_as_int(v), lane));
}
__device__ __forceinline__ unsigned short bf16rne(float x){
  unsigned u = __float_as_uint(x);
  return (unsigned short)((u + 0x7FFF + ((u >> 16) & 1)) >> 16);
}

// ================= bf16 MFMA GEMM: C = epi(A @ B^T_panels), 64x128 tile =================
template<int EPI, int OUTBF>
__global__ __launch_bounds__(256)
void mgemm_k(const unsigned short* __restrict__ A, const unsigned short* __restrict__ B,
             void* __restrict__ Cv, int K, int lda, int ldb, int ldc,
             long sA, long sB, long sC,
             const float* __restrict__ bias,
             const float* __restrict__ e1, long sE1, const float* __restrict__ e2)
{
  const int bz = blockIdx.z;
  A += (long)bz * sA; B += (long)bz * sB;
  __shared__ char lds[12288];
  char* As = lds;
  char* Bs = lds + 4096;
  const int tid = threadIdx.x;
  const int l = tid & 63, wid = tid >> 6;
  const int wr = wid >> 1, wc = wid & 1;
  const int m0 = blockIdx.y * 64, n0 = blockIdx.x * 128;
  const int lrow = l & 15, lslot = (l >> 4) << 4;
  f32x4 acc[2][4] = {};

  for (int kk = 0; kk < K; kk += 32) {
    {
      int row = tid >> 2, c16 = (tid & 3) << 4;
      int sw = c16 ^ (((row >> 1) & 3) << 4);
      uint4 va = *(const uint4*)(A + (long)(m0 + row) * lda + kk + (c16 >> 1));
      *(uint4*)(As + row * 64 + sw) = va;
    }
#pragma unroll
    for (int i = 0; i < 2; ++i) {
      int idx = i * 256 + tid;
      int row = idx >> 2, c16 = (idx & 3) << 4;
      int sw = c16 ^ (((row >> 1) & 3) << 4);
      uint4 vb = *(const uint4*)(B + (long)(n0 + row) * ldb + kk + (c16 >> 1));
      *(uint4*)(Bs + row * 64 + sw) = vb;
    }
    __syncthreads();
    bf16x8 af[2], bfr[4];
#pragma unroll
    for (int t = 0; t < 2; ++t) {
      int ra = wr * 32 + t * 16 + lrow;
      af[t]  = *(const bf16x8*)(As + ra * 64 + (lslot ^ (((ra >> 1) & 3) << 4)));
    }
#pragma unroll
    for (int t = 0; t < 4; ++t) {
      int rb = wc * 64 + t * 16 + lrow;
      bfr[t] = *(const bf16x8*)(Bs + rb * 64 + (lslot ^ (((rb >> 1) & 3) << 4)));
    }
#pragma unroll
    for (int mi = 0; mi < 2; ++mi)
#pragma unroll
      for (int ni = 0; ni < 4; ++ni)
        acc[mi][ni] = __builtin_amdgcn_mfma_f32_16x16x32_bf16(af[mi], bfr[ni], acc[mi][ni], 0, 0, 0);
    __syncthreads();
  }

  float* Cf = (float*)Cv; unsigned short* Cb = (unsigned short*)Cv;
  if (OUTBF) Cb += (long)bz * sC; else Cf += (long)bz * sC;
  if (e1) e1 += (long)bz * sE1;
#pragma unroll
  for (int mi = 0; mi < 2; ++mi)
#pragma unroll
  for (int ni = 0; ni < 4; ++ni)
#pragma unroll
  for (int r = 0; r < 4; ++r) {
    int m = m0 + wr * 32 + mi * 16 + ((l >> 4) << 2) + r;
    int n = n0 + wc * 64 + ni * 16 + (l & 15);
    float v = acc[mi][ni][r];
    if (EPI == 1) v = tanhf(v + bias[n]);
    else if (EPI == 3) v = fmaxf(v + bias[n], 0.f);
    else if (EPI == 4) v = v + e1[m] * e2[n];
    if (OUTBF) Cb[(long)m * ldc + n] = bf16rne(v);
    else       Cf[(long)m * ldc + n] = v;
  }
}

// ===== A-score GEMM: A = exp(tanh(tpw@tc^T)) zero-diag; emits A, W=-A, colsum partials =====
// grid (8 nx, 16 my, 8 bz). csp[my][b*1024+n] unique-writer per block.
__global__ __launch_bounds__(256)
void mgemm_score_k(const unsigned short* __restrict__ A, const unsigned short* __restrict__ B,
                   float* __restrict__ Ab, float* __restrict__ Wb, float* __restrict__ csp)
{
  const int bz = blockIdx.z;
  A += (long)bz * 524288; B += (long)bz * 524288;
  __shared__ char lds[12288];
  __shared__ float csb[2][128];
  char* As = lds; char* Bs = lds + 4096;
  const int tid = threadIdx.x;
  const int l = tid & 63, wid = tid >> 6;
  const int wr = wid >> 1, wc = wid & 1;
  const int m0 = blockIdx.y * 64, n0 = blockIdx.x * 128;
  const int lrow = l & 15, lslot = (l >> 4) << 4;
  f32x4 acc[2][4] = {};
  for (int kk = 0; kk < 512; kk += 32) {
    {
      int row = tid >> 2, c16 = (tid & 3) << 4;
      int sw = c16 ^ (((row >> 1) & 3) << 4);
      uint4 va = *(const uint4*)(A + (long)(m0 + row) * 512 + kk + (c16 >> 1));
      *(uint4*)(As + row * 64 + sw) = va;
    }
#pragma unroll
    for (int i = 0; i < 2; ++i) {
      int idx = i * 256 + tid;
      int row = idx >> 2, c16 = (idx & 3) << 4;
      int sw = c16 ^ (((row >> 1) & 3) << 4);
      uint4 vb = *(const uint4*)(B + (long)(n0 + row) * 512 + kk + (c16 >> 1));
      *(uint4*)(Bs + row * 64 + sw) = vb;
    }
    __syncthreads();
    bf16x8 af[2], bfr[4];
#pragma unroll
    for (int t = 0; t < 2; ++t) {
      int ra = wr * 32 + t * 16 + lrow;
      af[t]  = *(const bf16x8*)(As + ra * 64 + (lslot ^ (((ra >> 1) & 3) << 4)));
    }
#pragma unroll
    for (int t = 0; t < 4; ++t) {
      int rb = wc * 64 + t * 16 + lrow;
      bfr[t] = *(const bf16x8*)(Bs + rb * 64 + (lslot ^ (((rb >> 1) & 3) << 4)));
    }
#pragma unroll
    for (int mi = 0; mi < 2; ++mi)
#pragma unroll
      for (int ni = 0; ni < 4; ++ni)
        acc[mi][ni] = __builtin_amdgcn_mfma_f32_16x16x32_bf16(af[mi], bfr[ni], acc[mi][ni], 0, 0, 0);
    __syncthreads();
  }
  Ab += (long)bz * 1048576; Wb += (long)bz * 1048576;
  float cst[4] = {0.f, 0.f, 0.f, 0.f};
#pragma unroll
  for (int mi = 0; mi < 2; ++mi)
#pragma unroll
  for (int ni = 0; ni < 4; ++ni)
#pragma unroll
  for (int r = 0; r < 4; ++r) {
    int m = m0 + wr * 32 + mi * 16 + ((l >> 4) << 2) + r;
    int n = n0 + wc * 64 + ni * 16 + (l & 15);
    float v = (m == n) ? 0.f : expf(tanhf(acc[mi][ni][r]));
    Ab[(long)m * 1024 + n] = v;
    Wb[(long)m * 1024 + n] = -v;
    cst[ni] += v;
  }
#pragma unroll
  for (int ni = 0; ni < 4; ++ni) {
    cst[ni] += __shfl_xor(cst[ni], 16, 64);
    cst[ni] += __shfl_xor(cst[ni], 32, 64);
  }
  if ((l >> 4) == 0) {
#pragma unroll
    for (int ni = 0; ni < 4; ++ni) csb[wr][wc * 64 + ni * 16 + (l & 15)] = cst[ni];
  }
  __syncthreads();
  if (tid < 128)
    csp[(long)blockIdx.y * 8192 + bz * 1024 + n0 + tid] = csb[0][tid] + csb[1][tid];
}

// ========== dual-output variant for pinp / cinp, 64x128 tile, bf16 out ==========
__global__ __launch_bounds__(256)
void mgemm_pc_k(const unsigned short* __restrict__ A1, const unsigned short* __restrict__ A2,
                const unsigned short* __restrict__ B,
                unsigned short* __restrict__ C1, unsigned short* __restrict__ C2,
                int K, int lda, int ldb, int ldc, long sA, long sB, long sC,
                const float* __restrict__ e1, long sE1, const float* __restrict__ e2)
{
  const int z = blockIdx.z;
  const int bz = z & 7;
  const bool second = (z >= 8);
  const unsigned short* A = (second ? A2 : A1) + (long)bz * sA;
  const unsigned short* Bp = B + (long)bz * sB;
  unsigned short* C = (second ? C2 : C1) + (long)bz * sC;
  const float* e1p = second ? nullptr : (e1 + (long)bz * sE1);
  __shared__ char lds[12288];
  char* As = lds; char* Bs = lds + 4096;
  const int tid = threadIdx.x;
  const int l = tid & 63, wid = tid >> 6;
  const int wr = wid >> 1, wc = wid & 1;
  const int m0 = blockIdx.y * 64, n0 = blockIdx.x * 128;
  const int lrow = l & 15, lslot = (l >> 4) << 4;
  f32x4 acc[2][4] = {};
  for (int kk = 0; kk < K; kk += 32) {
    {
      int row = tid >> 2, c16 = (tid & 3) << 4;
      int sw = c16 ^ (((row >> 1) & 3) << 4);
      uint4 va = *(const uint4*)(A + (long)(m0 + row) * lda + kk + (c16 >> 1));
      *(uint4*)(As + row * 64 + sw) = va;
    }
#pragma unroll
    for (int i = 0; i < 2; ++i) {
      int idx = i * 256 + tid;
      int row = idx >> 2, c16 = (idx & 3) << 4;
      int sw = c16 ^ (((row >> 1) & 3) << 4);
      uint4 vb = *(const uint4*)(Bp + (long)(n0 + row) * ldb + kk + (c16 >> 1));
      *(uint4*)(Bs + row * 64 + sw) = vb;
    }
    __syncthreads();
    bf16x8 af[2], bfr[4];
#pragma unroll
    for (int t = 0; t < 2; ++t) {
      int ra = wr * 32 + t * 16 + lrow;
      af[t]  = *(const bf16x8*)(As + ra * 64 + (lslot ^ (((ra >> 1) & 3) << 4)));
    }
#pragma unroll
    for (int t = 0; t < 4; ++t) {
      int rb = wc * 64 + t * 16 + lrow;
      bfr[t] = *(const bf16x8*)(Bs + rb * 64 + (lslot ^ (((rb >> 1) & 3) << 4)));
    }
#pragma unroll
    for (int mi = 0; mi < 2; ++mi)
#pragma unroll
      for (int ni = 0; ni < 4; ++ni)
        acc[mi][ni] = __builtin_amdgcn_mfma_f32_16x16x32_bf16(af[mi], bfr[ni], acc[mi][ni], 0, 0, 0);
    __syncthreads();
  }
#pragma unroll
  for (int mi = 0; mi < 2; ++mi)
#pragma unroll
  for (int ni = 0; ni < 4; ++ni)
#pragma unroll
  for (int r = 0; r < 4; ++r) {
    int m = m0 + wr * 32 + mi * 16 + ((l >> 4) << 2) + r;
    int n = n0 + wc * 64 + ni * 16 + (l & 15);
    float v = acc[mi][ni][r];
    if (e1p) v = v + e1p[m] * e2[n];
    C[(long)m * ldc + n] = bf16rne(v);
  }
}

// ---------------- feature split (+ strb bf16 emit) ----------------
__global__ void split_k(const float* __restrict__ in, float* __restrict__ sem,
                        float* __restrict__ str, unsigned short* __restrict__ strb){
  long row = blockIdx.x;
  int c = threadIdx.x << 2;
  float4 v = ld4(in + row * 1024 + c);
  bool isStr = (c >= 256 && c < 512) || (c >= 768);
  int off;
  float* dst;
  if (c < 256)      { dst = sem + row * 512 + c;               off = c; }
  else if (c < 512) { dst = str + row * 512 + (c - 256);       off = c - 256; }
  else if (c < 768) { dst = sem + row * 512 + 256 + (c - 512); off = 0; }
  else              { dst = str + row * 512 + 256 + (c - 768); off = 256 + (c - 768); }
  *(float4*)dst = v;
  if (isStr) {
    unsigned lo = bf16rne(v.x) | ((unsigned)bf16rne(v.y) << 16);
    unsigned hi = bf16rne(v.z) | ((unsigned)bf16rne(v.w) << 16);
    uint2 w; w.x = lo; w.y = hi;
    *(uint2*)(strb + row * 512 + off) = w;
  }
}

// ---------------- fused 3-weight cast ----------------
__global__ void castw3_k(const float* __restrict__ Wtp, const float* __restrict__ Wtc,
                         const float* __restrict__ Wfz,
                         unsigned short* __restrict__ wtpb, unsigned short* __restrict__ wtcb,
                         unsigned short* __restrict__ wfzb){
  long i = ((long)blockIdx.x * 256 + threadIdx.x) << 2;
  const float* src; unsigned short* dst; long off;
  if (i < 262144)      { src = Wtp; dst = wtpb; off = i; }
  else if (i < 524288) { src = Wtc; dst = wtcb; off = i - 262144; }
  else                 { src = Wfz; dst = wfzb; off = i - 524288; }
  float4 v = ld4(src + off);
  unsigned lo = bf16rne(v.x) | ((unsigned)bf16rne(v.y) << 16);
  unsigned hi = bf16rne(v.z) | ((unsigned)bf16rne(v.w) << 16);
  uint2 w; w.x = lo; w.y = hi;
  *(uint2*)(dst + off) = w;
}

__global__ __launch_bounds__(256) void castT_k(const float* __restrict__ src, unsigned short* __restrict__ dst,
                                               int R, int C, long sS, long sD){
  int b = blockIdx.z;
  src += (long)b * sS; dst += (long)b * sD;
  __shared__ float t[32][33];
  int r0 = blockIdx.y * 32, c0 = blockIdx.x * 32;
  int tx = threadIdx.x & 31, ty = threadIdx.x >> 5;
#pragma unroll
  for (int j = 0; j < 32; j += 8)
    t[ty + j][tx] = src[(long)(r0 + ty + j) * C + c0 + tx];
  __syncthreads();
#pragma unroll
  for (int j = 0; j < 32; j += 8)
    dst[(long)(c0 + ty + j) * R + r0 + tx] = bf16rne(t[tx][ty + j]);
}

__global__ void semcopy_k(const float* __restrict__ sem, unsigned short* __restrict__ finpb){
  long idx = ((long)blockIdx.x * 256 + threadIdx.x) << 2;
  long row = idx >> 9; int col = (int)(idx & 511);
  float4 v = ld4(sem + idx);
  unsigned lo = bf16rne(v.x) | ((unsigned)bf16rne(v.y) << 16);
  unsigned hi = bf16rne(v.z) | ((unsigned)bf16rne(v.w) << 16);
  uint2 w; w.x = lo; w.y = hi;
  *(uint2*)(finpb + row * 1536 + col) = w;
}

// ---------------- f_i = exp(tanh(str . wfi)) ----------------
__global__ void fi_k(const float* __restrict__ str, const float* __restrict__ wfi, float* __restrict__ fi){
  int row = blockIdx.x * 4 + (threadIdx.x >> 6);
  int lane = threadIdx.x & 63;
  const float* p = str + (long)row * 512;
  float acc = 0.f;
  for (int c = lane; c < 512; c += 64) acc = fmaf(p[c], wfi[c], acc);
  for (int off = 32; off; off >>= 1) acc += __shfl_down(acc, off, 64);
  if (lane == 0) fi[row] = expf(tanhf(acc));
}

// ---------------- buildfix: W row0=fi, diag=colsum; emit Cold0 hi/lo ----------------
// grid (16 rowchunks, 8 batches), 256 thr. Values computed from source (no RW race).
__global__ void buildfix_k(const float* __restrict__ csp, const float* __restrict__ fi,
                           float* __restrict__ W,
                           unsigned short* __restrict__ Ch0, unsigned short* __restrict__ Cl0){
  int rc = blockIdx.x, b = blockIdx.y;
  int tid = threadIdx.x;
  __shared__ float cs[64];
  int i0 = rc * 64;
  if (tid < 64) {
    float s = 0.f;
#pragma unroll
    for (int p = 0; p < 16; ++p) s += csp[(long)p * 8192 + b * 1024 + i0 + tid];
    cs[tid] = s;
  }
  __syncthreads();
  float* Wb = W + (long)b * 1048576;
  const float* fib = fi + b * 1024;
  if (rc == 0) {
    for (int j = tid; j < 1024; j += 256) Wb[j] = fib[j];
  }
  if (tid < 64) {
    int i = i0 + tid;
    if (i != 0) Wb[(long)i * 1024 + i] = cs[tid];
  }
  unsigned short* ChB_ = Ch0 + b * 65536;
  unsigned short* ClB_ = Cl0 + b * 65536;
  for (int e = tid; e < 4096; e += 256) {
    int ii = e >> 6, j = e & 63;
    int i = i0 + ii;
    float v;
    if (i == 0)      v = fib[j];
    else if (i == j) v = cs[ii];
    else             v = Wb[(long)i * 1024 + j];   // = -A, written by score kernel
    unsigned short h = bf16rne(v);
    float hf = __uint_as_float((unsigned)h << 16);
    ChB_[(long)i * 64 + j] = h;
    ClB_[(long)i * 64 + j] = bf16rne(v - hf);
  }
}

// ---------------- GJ fused: {two-level 64x64 diag inverse in LDS} + {Rnew 64-col chunk} ----------------
#define G16C(c) { float bc = rdlane(e[(c)], K16_);               \
                  float z  = piv ? 0.f : e[(c)];                 \
                  e[(c)] = fmaf(-t, bc, z); }
#define G16S(k) { enum { K16_ = (k) };                           \
    float pk = rdlane(e[K16_], K16_);                            \
    float pr = 1.f / pk;                                         \
    float f  = e[K16_];                                          \
    bool piv = (mm == K16_);                                     \
    float t  = piv ? -pr : f * pr;                               \
    G16C(0) G16C(1) G16C(2) G16C(3) G16C(4) G16C(5) G16C(6) G16C(7) \
    G16C(8) G16C(9) G16C(10) G16C(11) G16C(12) G16C(13) G16C(14) G16C(15) \
    e[K16_] = -t; }

__global__ __launch_bounds__(256) void gj_fprep2_k(const float* __restrict__ W,
                                                   float* __restrict__ Rnew,
                                                   unsigned short* __restrict__ RTh, unsigned short* __restrict__ RTl,
                                                   int k0){
  __shared__ float P[64][65];
  __shared__ float Rt[16][68];
  __shared__ float S[64][68];
  int b = blockIdx.x;
  int J = blockIdx.y * 64;
  int tid = threadIdx.x;
  int l = tid & 63, w = tid >> 6;
  int q16 = w << 4;
  int mm = l & 15;
  const float* Wr = W + (long)b * 1048576 + (long)k0 * 1024 + J;
  for (int i = tid; i < 1024; i += 256) {
    int q = i >> 4, j4 = (i & 15) << 2;
    *(float4*)&S[q][j4] = ld4(Wr + (long)q * 1024 + j4);
  }
  const float* Wd = W + (long)b * 1048576 + (long)(k0 + l) * 1024 + k0 + q16;
#pragma unroll
  for (int c = 0; c < 16; c += 4) {
    float4 v = ld4(Wd + c);
    P[l][q16 + c] = v.x; P[l][q16 + c + 1] = v.y;
    P[l][q16 + c + 2] = v.z; P[l][q16 + c + 3] = v.w;
  }
  __syncthreads();
  for (int kb = 0; kb < 4; ++kb) {
    int kbase = kb << 4;
    float e[16];
#pragma unroll
    for (int c = 0; c < 16; ++c) e[c] = P[kbase + mm][kbase + c];
    G16S(0) G16S(1) G16S(2) G16S(3) G16S(4) G16S(5) G16S(6) G16S(7)
    G16S(8) G16S(9) G16S(10) G16S(11) G16S(12) G16S(13) G16S(14) G16S(15)
    float Cc[16];
#pragma unroll
    for (int c = 0; c < 16; ++c) Cc[c] = P[l][kbase + c];
    int c4 = q16 + ((l >> 4) << 2);
    float r0, r1, r2, r3;
    if (w == kb) {
      int g = l >> 4;
      if (g == 0)      { r0 = e[0];  r1 = e[1];  r2 = e[2];  r3 = e[3];  }
      else if (g == 1) { r0 = e[4];  r1 = e[5];  r2 = e[6];  r3 = e[7];  }
      else if (g == 2) { r0 = e[8];  r1 = e[9];  r2 = e[10]; r3 = e[11]; }
      else             { r0 = e[12]; r1 = e[13]; r2 = e[14]; r3 = e[15]; }
    } else {
      r0 = r1 = r2 = r3 = 0.f;
#pragma unroll
      for (int j = 0; j < 16; ++j) {
        float ej = e[j];
        r0 = fmaf(ej, P[kbase + j][c4 + 0], r0);
        r1 = fmaf(ej, P[kbase + j][c4 + 1], r1);
        r2 = fmaf(ej, P[kbase + j][c4 + 2], r2);
        r3 = fmaf(ej, P[kbase + j][c4 + 3], r3);
      }
    }
    Rt[mm][c4 + 0] = r0; Rt[mm][c4 + 1] = r1;
    Rt[mm][c4 + 2] = r2; Rt[mm][c4 + 3] = r3;
    __syncthreads();
    if (l >= kbase && l < kbase + 16) {
#pragma unroll
      for (int c = 0; c < 16; c += 4) {
        float4 v = *(float4*)&Rt[l - kbase][q16 + c];
        P[l][q16 + c] = v.x; P[l][q16 + c + 1] = v.y;
        P[l][q16 + c + 2] = v.z; P[l][q16 + c + 3] = v.w;
      }
    } else {
      float acc[16];
      bool colKb = (w == kb);
#pragma unroll
      for (int c = 0; c < 16; ++c) acc[c] = colKb ? 0.f : P[l][q16 + c];
#pragma unroll
      for (int j = 0; j < 16; ++j) {
        float cj = Cc[j];
        float4 v0 = *(float4*)&Rt[j][q16 + 0];
        float4 v1 = *(float4*)&Rt[j][q16 + 4];
        float4 v2 = *(float4*)&Rt[j][q16 + 8];
        float4 v3 = *(float4*)&Rt[j][q16 + 12];
        acc[0]  = fmaf(-cj, v0.x, acc[0]);  acc[1]  = fmaf(-cj, v0.y, acc[1]);
        acc[2]  = fmaf(-cj, v0.z, acc[2]);  acc[3]  = fmaf(-cj, v0.w, acc[3]);
        acc[4]  = fmaf(-cj, v1.x, acc[4]);  acc[5]  = fmaf(-cj, v1.y, acc[5]);
        acc[6]  = fmaf(-cj, v1.z, acc[6]);  acc[7]  = fmaf(-cj, v1.w, acc[7]);
        acc[8]  = fmaf(-cj, v2.x, acc[8]);  acc[9]  = fmaf(-cj, v2.y, acc[9]);
        acc[10] = fmaf(-cj, v2.z, acc[10]); acc[11] = fmaf(-cj, v2.w, acc[11]);
        acc[12] = fmaf(-cj, v3.x, acc[12]); acc[13] = fmaf(-cj, v3.y, acc[13]);
        acc[14] = fmaf(-cj, v3.z, acc[14]); acc[15] = fmaf(-cj, v3.w, acc[15]);
      }
#pragma unroll
      for (int c = 0; c < 16; ++c) P[l][q16 + c] = acc[c];
    }
    __syncthreads();
  }
  int p = tid & 63;
  float acc2[16] = {};
  for (int q = 0; q < 64; ++q) {
    float d = P[p][q];
#pragma unroll
    for (int c = 0; c < 16; ++c) acc2[c] = fmaf(d, S[q][q16 + c], acc2[c]);
  }
  __syncthreads();
#pragma unroll
  for (int c = 0; c < 16; ++c) {
    int jg = J + q16 + c;
    float v = acc2[c];
    if (jg >= k0 && jg < k0 + 64) v = P[p][jg - k0];
    S[p][q16 + c] = v;
  }
  __syncthreads();
  float* Rb = Rnew + (long)b * 65536 + J;
  for (int i = tid; i < 1024; i += 256) {
    int rr = i >> 4, j4 = (i & 15) << 2;
    *(float4*)(Rb + (long)rr * 1024 + j4) = *(float4*)&S[rr][j4];
  }
  unsigned short* th = RTh + (long)b * 65536 + (long)J * 64;
  unsigned short* tl = RTl + (long)b * 65536 + (long)J * 64;
  for (int i = tid; i < 4096; i += 256) {
    int jl = i >> 6, pp = i & 63;
    float v = S[pp][jl];
    unsigned short h = bf16rne(v);
    float hf = __uint_as_float((unsigned)h << 16);
    th[i] = h;
    tl[i] = bf16rne(v - hf);
  }
}

// ---------------- GJ trailing update: 64x64 tiles, bf16x3 MFMA, global-direct fragments ----------------
__global__ __launch_bounds__(256) void gupd_k(const unsigned short* __restrict__ Ch, const unsigned short* __restrict__ Cl,
                                              const unsigned short* __restrict__ RTh, const unsigned short* __restrict__ RTl,
                                              const float* __restrict__ Rnew, float* __restrict__ W,
                                              unsigned short* __restrict__ ChN, unsigned short* __restrict__ ClN, int k0){
  int b = blockIdx.x;
  const unsigned short* Ahp = Ch + (long)b * 65536;
  const unsigned short* Alp = Cl + (long)b * 65536;
  const unsigned short* Bhp = RTh + (long)b * 65536;
  const unsigned short* Blp = RTl + (long)b * 65536;
  const float* Rb = Rnew + (long)b * 65536;
  float* Wb = W + (long)b * 1048576;
  unsigned short* CnH = ChN + (long)b * 65536;
  unsigned short* CnL = ClN + (long)b * 65536;
  const int tid = threadIdx.x, l = tid & 63, wid = tid >> 6;
  const int wr = wid >> 1, wc = wid & 1;
  const int m0 = blockIdx.y * 64, n0 = blockIdx.z * 64;
  const int lrow = l & 15, kc8 = (l >> 4) << 3;
  f32x4 acc[2][2] = {};
#pragma unroll
  for (int kk = 0; kk < 2; ++kk) {
    bf16x8 ah[2], al4[2], bh[2], bl4[2];
#pragma unroll
    for (int t = 0; t < 2; ++t) {
      int ra = m0 + wr * 32 + t * 16 + lrow;
      long offa = (long)ra * 64 + kk * 32 + kc8;
      ah[t]  = *(const bf16x8*)(Ahp + offa);
      al4[t] = *(const bf16x8*)(Alp + offa);
      int rb = n0 + wc * 32 + t * 16 + lrow;
      long offb = (long)rb * 64 + kk * 32 + kc8;
      bh[t]  = *(const bf16x8*)(Bhp + offb);
      bl4[t] = *(const bf16x8*)(Blp + offb);
    }
#pragma unroll
    for (int mi = 0; mi < 2; ++mi)
#pragma unroll
      for (int ni = 0; ni < 2; ++ni) {
        acc[mi][ni] = __builtin_amdgcn_mfma_f32_16x16x32_bf16(ah[mi],  bh[ni],  acc[mi][ni], 0, 0, 0);
        acc[mi][ni] = __builtin_amdgcn_mfma_f32_16x16x32_bf16(ah[mi],  bl4[ni], acc[mi][ni], 0, 0, 0);
        acc[mi][ni] = __builtin_amdgcn_mfma_f32_16x16x32_bf16(al4[mi], bh[ni],  acc[mi][ni], 0, 0, 0);
      }
  }
#pragma unroll
  for (int mi = 0; mi < 2; ++mi)
#pragma unroll
  for (int ni = 0; ni < 2; ++ni)
#pragma unroll
  for (int r = 0; r < 4; ++r) {
    int m = m0 + wr * 32 + mi * 16 + ((l >> 4) << 2) + r;
    int n = n0 + wc * 32 + ni * 16 + (l & 15);
    bool rowK = (m >= k0 && m < k0 + 64);
    bool colK = (n >= k0 && n < k0 + 64);
    float v;
    if (rowK)      v = Rb[(long)(m - k0) * 1024 + n];
    else if (colK) v = -acc[mi][ni][r];
    else           v = Wb[(long)m * 1024 + n] - acc[mi][ni][r];
    Wb[(long)m * 1024 + n] = v;
    int cn = n - k0 - 64;
    if (cn >= 0 && cn < 64) {
      unsigned short h = bf16rne(v);
      float hf = __uint_as_float((unsigned)h << 16);
      CnH[(long)m * 64 + cn] = h;
      CnL[(long)m * 64 + cn] = bf16rne(v - hf);
    }
  }
}

// ---------------- d0, diag, df col 0 ----------------
__global__ void ddiag_k(const float* __restrict__ W, const float* __restrict__ fi,
                        float* __restrict__ d0, float* __restrict__ diag, float* __restrict__ dfout){
  int t = blockIdx.x * 256 + threadIdx.x;
  int b = t >> 10, i = t & 1023;
  const float* Wb = W + (long)b * TT * TT;
  float dv = fi[t] * Wb[(long)i * TT];
  d0[t] = dv;
  diag[t] = Wb[(long)i * TT + i];
  dfout[(long)b * TT * 1025 + (long)i * 1025] = dv;
}

// ---------------- dx: compute, emit bf16 dx + bf16 dx^T + df store ----------------
__global__ __launch_bounds__(256) void dx_k(const float* __restrict__ A, const float* __restrict__ W,
                                            const float* __restrict__ diag, float* __restrict__ dfout,
                                            unsigned short* __restrict__ dxb, unsigned short* __restrict__ dxTb){
  int b = blockIdx.z;
  int i0 = blockIdx.y * 64, j0 = blockIdx.x * 64;
  const float* Wb = W + (long)b * TT * TT;
  const float* Ab = A + (long)b * TT * TT;
  __shared__ float Ls[64][65];
  __shared__ float Sx[64][65];
  int tid = threadIdx.x;
  for (int idx = tid; idx < 4096; idx += 256) {
    int r = idx >> 6, c = idx & 63;
    Ls[r][c] = Wb[(long)(j0 + r) * TT + i0 + c];
  }
  __syncthreads();
  for (int idx = tid; idx < 4096; idx += 256) {
    int r = idx >> 6, c = idx & 63;
    int i = i0 + r, j = j0 + c;
    float a = Ab[(long)i * TT + j];
    float v = 0.f;
    if (j > 0) v = a * diag[b * TT + j];
    if (i > 0) v -= a * Ls[c][r];
    dxb[(long)b * 1048576 + (long)i * 1024 + j] = bf16rne(v);
    Sx[r][c] = v;
  }
  __syncthreads();
  float* dfb = dfout + (long)b * TT * 1025;
  unsigned short* dtb = dxTb + (long)b * 1048576;
  for (int idx = tid; idx < 4096; idx += 256) {
    int r = idx >> 6, c = idx & 63;
    float v = Sx[c][r];
    dfb[(long)(j0 + r) * 1025 + i0 + 1 + c] = v;
    dtb[(long)(j0 + r) * 1024 + i0 + c] = bf16rne(v);
  }
}

extern "C" void kernel_launch(void* const* d_in, const int* in_sizes, int n_in,
                              void* d_out, int out_size, void* d_ws, size_t ws_size,
                              hipStream_t stream){
  const float* input   = (const float*)d_in[0];
  const float* Wtp     = (const float*)d_in[1];
  const float* btp     = (const float*)d_in[2];
  const float* Wtc     = (const float*)d_in[3];
  const float* btc     = (const float*)d_in[4];
  const float* wfi     = (const float*)d_in[5];
  const float* Wbil    = (const float*)d_in[6];
  const float* exparam = (const float*)d_in[7];
  const float* Wfz     = (const float*)d_in[8];
  const float* bfz     = (const float*)d_in[9];

  if (ws_size < 147000000UL) return;

  float* ws   = (float*)d_ws;
  float* sem   = ws;                    // 4,194,304 f
  float* strv  = ws + 4194304;          // 4,194,304 f  [later: dxb bf16]
  float* Abuf  = ws + 8388608;          // 8,388,608 f  [later: finpb bf16]
  float* Wbuf  = ws + 16777216;         // 8,388,608 f
  unsigned short* strb = (unsigned short*)(ws + 25165824);
  unsigned short* tpb  = (unsigned short*)(ws + 27262976);
  unsigned short* tcb  = (unsigned short*)(ws + 29360128);
  unsigned short* tpwb = (unsigned short*)(ws + 31457280);
  unsigned short* wtpb = (unsigned short*)(ws + 33554432);
  unsigned short* wtcb = (unsigned short*)(ws + 33685504);
  unsigned short* wbilT= (unsigned short*)(ws + 33816576);
  unsigned short* wfzb = (unsigned short*)(ws + 33947648);
  float* fi    = ws + 34340864;         // 8192
  float* csp   = ws + 34349056;         // 131,072 (16 partials x 8192)
  float* d0    = ws + 34480128;         // 8192
  float* dg    = ws + 34488320;         // 8192
  float* Rnew  = ws + 34496512;         // 524,288
  unsigned short* ChA = (unsigned short*)(ws + 35020800);  // 8x1024x64 bf16
  unsigned short* ClA = (unsigned short*)(ws + 35282944);
  unsigned short* ChB = (unsigned short*)(ws + 35545088);
  unsigned short* ClB = (unsigned short*)(ws + 35807232);
  unsigned short* RTh = (unsigned short*)(ws + 36069376);
  unsigned short* RTl = (unsigned short*)(ws + 36331520);
  unsigned short* dxb   = (unsigned short*)strv;
  unsigned short* dxTb  = (unsigned short*)(ws + 25165824);
  unsigned short* semTb = (unsigned short*)(ws + 29360128);
  unsigned short* finpb = (unsigned short*)Abuf;

  float* outp = (float*)d_out;
  float* dfp  = outp + 4194304;

  split_k<<<8192, 256, 0, stream>>>(input, sem, strv, strb);
  castw3_k<<<1280, 256, 0, stream>>>(Wtp, Wtc, Wfz, wtpb, wtcb, wfzb);
  castT_k<<<dim3(16,16,1), 256, 0, stream>>>(Wbil, wbilT, 512, 512, 0, 0);
  fi_k<<<2048, 256, 0, stream>>>(strv, wfi, fi);
  mgemm_k<1,1><<<dim3(4,128,1),256,0,stream>>>(strb, wtpb, tpb, 512, 512, 512, 512, 0,0,0, btp, nullptr,0,nullptr);
  mgemm_k<1,1><<<dim3(4,128,1),256,0,stream>>>(strb, wtcb, tcb, 512, 512, 512, 512, 0,0,0, btc, nullptr,0,nullptr);
  mgemm_k<0,1><<<dim3(4,128,1),256,0,stream>>>(tpb, wbilT, tpwb, 512, 512, 512, 512, 0,0,0, nullptr, nullptr,0,nullptr);
  // fused A-score: A, W=-A, colsum partials
  mgemm_score_k<<<dim3(8,16,8),256,0,stream>>>(tpwb, tcb, Abuf, Wbuf, csp);
  castT_k<<<dim3(16,32,8), 256, 0, stream>>>(sem, semTb, 1024, 512, 524288, 524288);
  buildfix_k<<<dim3(16,8),256,0,stream>>>(csp, fi, Wbuf, ChA, ClA);
  // blocked in-place Gauss-Jordan: {fprep2(dinv+Rnew), gupd} x 16, batch-pinned to XCDs
  for (int s = 0; s < 16; ++s) {
    int k0 = s * NB;
    unsigned short* ChI = (s & 1) ? ChB : ChA;
    unsigned short* ClI = (s & 1) ? ClB : ClA;
    unsigned short* ChO = (s & 1) ? ChA : ChB;
    unsigned short* ClO = (s & 1) ? ClA : ClB;
    gj_fprep2_k<<<dim3(8,16),256,0,stream>>>(Wbuf, Rnew, RTh, RTl, k0);
    gupd_k<<<dim3(8,16,16),256,0,stream>>>(ChI, ClI, RTh, RTl, Rnew, Wbuf, ChO, ClO, k0);
  }
  ddiag_k<<<32,256,0,stream>>>(Wbuf, fi, d0, dg, dfp);
  dx_k<<<dim3(16,16,8),256,0,stream>>>(Abuf, Wbuf, dg, dfp, dxb, dxTb);
  semcopy_k<<<4096,256,0,stream>>>(sem, finpb);
  mgemm_pc_k<<<dim3(4,16,16),256,0,stream>>>(dxTb, dxb, semTb, finpb + 512, finpb + 1024,
                                             1024, 1024, 1024, 1536, 1048576, 524288, 1572864,
                                             d0, 1024, exparam);
  mgemm_k<3,0><<<dim3(4,128,1),256,0,stream>>>(finpb, wfzb, outp, 1536, 1536, 1536, 512, 0,0,0, bfz, nullptr,0,nullptr);
}

// Round 18
// 1016.807 us; speedup vs baseline: 1.1769x; 1.0074x over previous
//
#include <hip/hip_runtime.h>
#include <math.h>

#define TT 1024
#define NB 64

typedef float f32x4 __attribute__((ext_vector_type(4)));
typedef __bf16 bf16x8 __attribute__((ext_vector_type(8)));

__device__ __forceinline__ float4 ld4(const float* p){ return *(const float4*)p; }
__device__ __forceinline__ float rdlane(float v, int lane){
  return __int_as_float(__builtin_amdgcn_readlane(__float_as_int(v), lane));
}
__device__ __forceinline__ unsigned short bf16rne(float x){
  unsigned u = __float_as_uint(x);
  return (unsigned short)((u + 0x7FFF + ((u >> 16) & 1)) >> 16);
}

// ================= bf16 MFMA GEMM: C = epi(A @ B^T_panels), 64x128 tile =================
template<int EPI, int OUTBF>
__global__ __launch_bounds__(256)
void mgemm_k(const unsigned short* __restrict__ A, const unsigned short* __restrict__ B,
             void* __restrict__ Cv, int K, int lda, int ldb, int ldc,
             long sA, long sB, long sC,
             const float* __restrict__ bias,
             const float* __restrict__ e1, long sE1, const float* __restrict__ e2)
{
  const int bz = blockIdx.z;
  A += (long)bz * sA; B += (long)bz * sB;
  __shared__ char lds[12288];
  char* As = lds;
  char* Bs = lds + 4096;
  const int tid = threadIdx.x;
  const int l = tid & 63, wid = tid >> 6;
  const int wr = wid >> 1, wc = wid & 1;
  const int m0 = blockIdx.y * 64, n0 = blockIdx.x * 128;
  const int lrow = l & 15, lslot = (l >> 4) << 4;
  f32x4 acc[2][4] = {};

  for (int kk = 0; kk < K; kk += 32) {
    {
      int row = tid >> 2, c16 = (tid & 3) << 4;
      int sw = c16 ^ (((row >> 1) & 3) << 4);
      uint4 va = *(const uint4*)(A + (long)(m0 + row) * lda + kk + (c16 >> 1));
      *(uint4*)(As + row * 64 + sw) = va;
    }
#pragma unroll
    for (int i = 0; i < 2; ++i) {
      int idx = i * 256 + tid;
      int row = idx >> 2, c16 = (idx & 3) << 4;
      int sw = c16 ^ (((row >> 1) & 3) << 4);
      uint4 vb = *(const uint4*)(B + (long)(n0 + row) * ldb + kk + (c16 >> 1));
      *(uint4*)(Bs + row * 64 + sw) = vb;
    }
    __syncthreads();
    bf16x8 af[2], bfr[4];
#pragma unroll
    for (int t = 0; t < 2; ++t) {
      int ra = wr * 32 + t * 16 + lrow;
      af[t]  = *(const bf16x8*)(As + ra * 64 + (lslot ^ (((ra >> 1) & 3) << 4)));
    }
#pragma unroll
    for (int t = 0; t < 4; ++t) {
      int rb = wc * 64 + t * 16 + lrow;
      bfr[t] = *(const bf16x8*)(Bs + rb * 64 + (lslot ^ (((rb >> 1) & 3) << 4)));
    }
#pragma unroll
    for (int mi = 0; mi < 2; ++mi)
#pragma unroll
      for (int ni = 0; ni < 4; ++ni)
        acc[mi][ni] = __builtin_amdgcn_mfma_f32_16x16x32_bf16(af[mi], bfr[ni], acc[mi][ni], 0, 0, 0);
    __syncthreads();
  }

  float* Cf = (float*)Cv; unsigned short* Cb = (unsigned short*)Cv;
  if (OUTBF) Cb += (long)bz * sC; else Cf += (long)bz * sC;
  if (e1) e1 += (long)bz * sE1;
#pragma unroll
  for (int mi = 0; mi < 2; ++mi)
#pragma unroll
  for (int ni = 0; ni < 4; ++ni)
#pragma unroll
  for (int r = 0; r < 4; ++r) {
    int m = m0 + wr * 32 + mi * 16 + ((l >> 4) << 2) + r;
    int n = n0 + wc * 64 + ni * 16 + (l & 15);
    float v = acc[mi][ni][r];
    if (EPI == 1) v = tanhf(v + bias[n]);
    else if (EPI == 3) v = fmaxf(v + bias[n], 0.f);
    else if (EPI == 4) v = v + e1[m] * e2[n];
    if (OUTBF) Cb[(long)m * ldc + n] = bf16rne(v);
    else       Cf[(long)m * ldc + n] = v;
  }
}

// ===== A-score GEMM: A = exp(tanh(tpw@tc^T)) zero-diag; emits A, W=-A, colsum partials =====
__global__ __launch_bounds__(256)
void mgemm_score_k(const unsigned short* __restrict__ A, const unsigned short* __restrict__ B,
                   float* __restrict__ Ab, float* __restrict__ Wb, float* __restrict__ csp)
{
  const int bz = blockIdx.z;
  A += (long)bz * 524288; B += (long)bz * 524288;
  __shared__ char lds[12288];
  __shared__ float csb[2][128];
  char* As = lds; char* Bs = lds + 4096;
  const int tid = threadIdx.x;
  const int l = tid & 63, wid = tid >> 6;
  const int wr = wid >> 1, wc = wid & 1;
  const int m0 = blockIdx.y * 64, n0 = blockIdx.x * 128;
  const int lrow = l & 15, lslot = (l >> 4) << 4;
  f32x4 acc[2][4] = {};
  for (int kk = 0; kk < 512; kk += 32) {
    {
      int row = tid >> 2, c16 = (tid & 3) << 4;
      int sw = c16 ^ (((row >> 1) & 3) << 4);
      uint4 va = *(const uint4*)(A + (long)(m0 + row) * 512 + kk + (c16 >> 1));
      *(uint4*)(As + row * 64 + sw) = va;
    }
#pragma unroll
    for (int i = 0; i < 2; ++i) {
      int idx = i * 256 + tid;
      int row = idx >> 2, c16 = (idx & 3) << 4;
      int sw = c16 ^ (((row >> 1) & 3) << 4);
      uint4 vb = *(const uint4*)(B + (long)(n0 + row) * 512 + kk + (c16 >> 1));
      *(uint4*)(Bs + row * 64 + sw) = vb;
    }
    __syncthreads();
    bf16x8 af[2], bfr[4];
#pragma unroll
    for (int t = 0; t < 2; ++t) {
      int ra = wr * 32 + t * 16 + lrow;
      af[t]  = *(const bf16x8*)(As + ra * 64 + (lslot ^ (((ra >> 1) & 3) << 4)));
    }
#pragma unroll
    for (int t = 0; t < 4; ++t) {
      int rb = wc * 64 + t * 16 + lrow;
      bfr[t] = *(const bf16x8*)(Bs + rb * 64 + (lslot ^ (((rb >> 1) & 3) << 4)));
    }
#pragma unroll
    for (int mi = 0; mi < 2; ++mi)
#pragma unroll
      for (int ni = 0; ni < 4; ++ni)
        acc[mi][ni] = __builtin_amdgcn_mfma_f32_16x16x32_bf16(af[mi], bfr[ni], acc[mi][ni], 0, 0, 0);
    __syncthreads();
  }
  Ab += (long)bz * 1048576; Wb += (long)bz * 1048576;
  float cst[4] = {0.f, 0.f, 0.f, 0.f};
#pragma unroll
  for (int mi = 0; mi < 2; ++mi)
#pragma unroll
  for (int ni = 0; ni < 4; ++ni)
#pragma unroll
  for (int r = 0; r < 4; ++r) {
    int m = m0 + wr * 32 + mi * 16 + ((l >> 4) << 2) + r;
    int n = n0 + wc * 64 + ni * 16 + (l & 15);
    float v = (m == n) ? 0.f : expf(tanhf(acc[mi][ni][r]));
    Ab[(long)m * 1024 + n] = v;
    Wb[(long)m * 1024 + n] = -v;
    cst[ni] += v;
  }
#pragma unroll
  for (int ni = 0; ni < 4; ++ni) {
    cst[ni] += __shfl_xor(cst[ni], 16, 64);
    cst[ni] += __shfl_xor(cst[ni], 32, 64);
  }
  if ((l >> 4) == 0) {
#pragma unroll
    for (int ni = 0; ni < 4; ++ni) csb[wr][wc * 64 + ni * 16 + (l & 15)] = cst[ni];
  }
  __syncthreads();
  if (tid < 128)
    csp[(long)blockIdx.y * 8192 + bz * 1024 + n0 + tid] = csb[0][tid] + csb[1][tid];
}

// ========== dual-output variant for pinp / cinp, 64x128 tile, bf16 out ==========
__global__ __launch_bounds__(256)
void mgemm_pc_k(const unsigned short* __restrict__ A1, const unsigned short* __restrict__ A2,
                const unsigned short* __restrict__ B,
                unsigned short* __restrict__ C1, unsigned short* __restrict__ C2,
                int K, int lda, int ldb, int ldc, long sA, long sB, long sC,
                const float* __restrict__ e1, long sE1, const float* __restrict__ e2)
{
  const int z = blockIdx.z;
  const int bz = z & 7;
  const bool second = (z >= 8);
  const unsigned short* A = (second ? A2 : A1) + (long)bz * sA;
  const unsigned short* Bp = B + (long)bz * sB;
  unsigned short* C = (second ? C2 : C1) + (long)bz * sC;
  const float* e1p = second ? nullptr : (e1 + (long)bz * sE1);
  __shared__ char lds[12288];
  char* As = lds; char* Bs = lds + 4096;
  const int tid = threadIdx.x;
  const int l = tid & 63, wid = tid >> 6;
  const int wr = wid >> 1, wc = wid & 1;
  const int m0 = blockIdx.y * 64, n0 = blockIdx.x * 128;
  const int lrow = l & 15, lslot = (l >> 4) << 4;
  f32x4 acc[2][4] = {};
  for (int kk = 0; kk < K; kk += 32) {
    {
      int row = tid >> 2, c16 = (tid & 3) << 4;
      int sw = c16 ^ (((row >> 1) & 3) << 4);
      uint4 va = *(const uint4*)(A + (long)(m0 + row) * lda + kk + (c16 >> 1));
      *(uint4*)(As + row * 64 + sw) = va;
    }
#pragma unroll
    for (int i = 0; i < 2; ++i) {
      int idx = i * 256 + tid;
      int row = idx >> 2, c16 = (idx & 3) << 4;
      int sw = c16 ^ (((row >> 1) & 3) << 4);
      uint4 vb = *(const uint4*)(Bp + (long)(n0 + row) * ldb + kk + (c16 >> 1));
      *(uint4*)(Bs + row * 64 + sw) = vb;
    }
    __syncthreads();
    bf16x8 af[2], bfr[4];
#pragma unroll
    for (int t = 0; t < 2; ++t) {
      int ra = wr * 32 + t * 16 + lrow;
      af[t]  = *(const bf16x8*)(As + ra * 64 + (lslot ^ (((ra >> 1) & 3) << 4)));
    }
#pragma unroll
    for (int t = 0; t < 4; ++t) {
      int rb = wc * 64 + t * 16 + lrow;
      bfr[t] = *(const bf16x8*)(Bs + rb * 64 + (lslot ^ (((rb >> 1) & 3) << 4)));
    }
#pragma unroll
    for (int mi = 0; mi < 2; ++mi)
#pragma unroll
      for (int ni = 0; ni < 4; ++ni)
        acc[mi][ni] = __builtin_amdgcn_mfma_f32_16x16x32_bf16(af[mi], bfr[ni], acc[mi][ni], 0, 0, 0);
    __syncthreads();
  }
#pragma unroll
  for (int mi = 0; mi < 2; ++mi)
#pragma unroll
  for (int ni = 0; ni < 4; ++ni)
#pragma unroll
  for (int r = 0; r < 4; ++r) {
    int m = m0 + wr * 32 + mi * 16 + ((l >> 4) << 2) + r;
    int n = n0 + wc * 64 + ni * 16 + (l & 15);
    float v = acc[mi][ni][r];
    if (e1p) v = v + e1p[m] * e2[n];
    C[(long)m * ldc + n] = bf16rne(v);
  }
}

// ---------------- feature split (+ strb bf16 emit + fused fi) ----------------
__global__ void split_k(const float* __restrict__ in, float* __restrict__ sem,
                        float* __restrict__ str, unsigned short* __restrict__ strb,
                        const float* __restrict__ wfi, float* __restrict__ fi){
  __shared__ float red[4];
  long row = blockIdx.x;
  int c = threadIdx.x << 2;
  float4 v = ld4(in + row * 1024 + c);
  bool isStr = (c >= 256 && c < 512) || (c >= 768);
  int off;
  float* dst;
  if (c < 256)      { dst = sem + row * 512 + c;               off = c; }
  else if (c < 512) { dst = str + row * 512 + (c - 256);       off = c - 256; }
  else if (c < 768) { dst = sem + row * 512 + 256 + (c - 512); off = 0; }
  else              { dst = str + row * 512 + 256 + (c - 768); off = 256 + (c - 768); }
  *(float4*)dst = v;
  float d = 0.f;
  if (isStr) {
    unsigned lo = bf16rne(v.x) | ((unsigned)bf16rne(v.y) << 16);
    unsigned hi = bf16rne(v.z) | ((unsigned)bf16rne(v.w) << 16);
    uint2 w; w.x = lo; w.y = hi;
    *(uint2*)(strb + row * 512 + off) = w;
    d = v.x * wfi[off] + v.y * wfi[off + 1] + v.z * wfi[off + 2] + v.w * wfi[off + 3];
  }
#pragma unroll
  for (int o = 32; o; o >>= 1) d += __shfl_down(d, o, 64);
  int lane = threadIdx.x & 63, wv = threadIdx.x >> 6;
  if (lane == 0) red[wv] = d;
  __syncthreads();
  if (threadIdx.x == 0)
    fi[row] = expf(tanhf(red[0] + red[1] + red[2] + red[3]));
}

// ---------------- merged weight casts: 3 row-casts + Wbil transpose-cast ----------------
__global__ __launch_bounds__(256) void castmisc_k(const float* __restrict__ Wtp, const float* __restrict__ Wtc,
                                                  const float* __restrict__ Wfz, const float* __restrict__ Wbil,
                                                  unsigned short* __restrict__ wtpb, unsigned short* __restrict__ wtcb,
                                                  unsigned short* __restrict__ wfzb, unsigned short* __restrict__ wbilT){
  __shared__ float t[32][33];
  int bx = blockIdx.x;
  if (bx < 1280) {
    long i = ((long)bx * 256 + threadIdx.x) << 2;
    const float* src; unsigned short* dst; long off;
    if (i < 262144)      { src = Wtp; dst = wtpb; off = i; }
    else if (i < 524288) { src = Wtc; dst = wtcb; off = i - 262144; }
    else                 { src = Wfz; dst = wfzb; off = i - 524288; }
    float4 v = ld4(src + off);
    unsigned lo = bf16rne(v.x) | ((unsigned)bf16rne(v.y) << 16);
    unsigned hi = bf16rne(v.z) | ((unsigned)bf16rne(v.w) << 16);
    uint2 w; w.x = lo; w.y = hi;
    *(uint2*)(dst + off) = w;
  } else {
    int id = bx - 1280;                 // 0..255 -> 32x32 tiles of 512x512
    int r0 = (id >> 4) * 32, c0 = (id & 15) * 32;
    int tx = threadIdx.x & 31, ty = threadIdx.x >> 5;
#pragma unroll
    for (int j = 0; j < 32; j += 8)
      t[ty + j][tx] = Wbil[(long)(r0 + ty + j) * 512 + c0 + tx];
    __syncthreads();
#pragma unroll
    for (int j = 0; j < 32; j += 8)
      wbilT[(long)(c0 + ty + j) * 512 + r0 + tx] = bf16rne(t[tx][ty + j]);
  }
}

__global__ __launch_bounds__(256) void castT_k(const float* __restrict__ src, unsigned short* __restrict__ dst,
                                               int R, int C, long sS, long sD){
  int b = blockIdx.z;
  src += (long)b * sS; dst += (long)b * sD;
  __shared__ float t[32][33];
  int r0 = blockIdx.y * 32, c0 = blockIdx.x * 32;
  int tx = threadIdx.x & 31, ty = threadIdx.x >> 5;
#pragma unroll
  for (int j = 0; j < 32; j += 8)
    t[ty + j][tx] = src[(long)(r0 + ty + j) * C + c0 + tx];
  __syncthreads();
#pragma unroll
  for (int j = 0; j < 32; j += 8)
    dst[(long)(c0 + ty + j) * R + r0 + tx] = bf16rne(t[tx][ty + j]);
}

__global__ void semcopy_k(const float* __restrict__ sem, unsigned short* __restrict__ finpb){
  long idx = ((long)blockIdx.x * 256 + threadIdx.x) << 2;
  long row = idx >> 9; int col = (int)(idx & 511);
  float4 v = ld4(sem + idx);
  unsigned lo = bf16rne(v.x) | ((unsigned)bf16rne(v.y) << 16);
  unsigned hi = bf16rne(v.z) | ((unsigned)bf16rne(v.w) << 16);
  uint2 w; w.x = lo; w.y = hi;
  *(uint2*)(finpb + row * 1536 + col) = w;
}

// ---------------- buildfix: W row0=fi, diag=colsum; emit Cold0 hi/lo ----------------
__global__ void buildfix_k(const float* __restrict__ csp, const float* __restrict__ fi,
                           float* __restrict__ W,
                           unsigned short* __restrict__ Ch0, unsigned short* __restrict__ Cl0){
  int rc = blockIdx.x, b = blockIdx.y;
  int tid = threadIdx.x;
  __shared__ float cs[64];
  int i0 = rc * 64;
  if (tid < 64) {
    float s = 0.f;
#pragma unroll
    for (int p = 0; p < 16; ++p) s += csp[(long)p * 8192 + b * 1024 + i0 + tid];
    cs[tid] = s;
  }
  __syncthreads();
  float* Wb = W + (long)b * 1048576;
  const float* fib = fi + b * 1024;
  if (rc == 0) {
    for (int j = tid; j < 1024; j += 256) Wb[j] = fib[j];
  }
  if (tid < 64) {
    int i = i0 + tid;
    if (i != 0) Wb[(long)i * 1024 + i] = cs[tid];
  }
  unsigned short* ChB_ = Ch0 + b * 65536;
  unsigned short* ClB_ = Cl0 + b * 65536;
  for (int e = tid; e < 4096; e += 256) {
    int ii = e >> 6, j = e & 63;
    int i = i0 + ii;
    float v;
    if (i == 0)      v = fib[j];
    else if (i == j) v = cs[ii];
    else             v = Wb[(long)i * 1024 + j];
    unsigned short h = bf16rne(v);
    float hf = __uint_as_float((unsigned)h << 16);
    ChB_[(long)i * 64 + j] = h;
    ClB_[(long)i * 64 + j] = bf16rne(v - hf);
  }
}

// ---------------- GJ fused: {two-level 64x64 diag inverse in LDS} + {Rnew 64-col chunk} ----------------
#define G16C(c) { float bc = rdlane(e[(c)], K16_);               \
                  float z  = piv ? 0.f : e[(c)];                 \
                  e[(c)] = fmaf(-t, bc, z); }
#define G16S(k) { enum { K16_ = (k) };                           \
    float pk = rdlane(e[K16_], K16_);                            \
    float pr = 1.f / pk;                                         \
    float f  = e[K16_];                                          \
    bool piv = (mm == K16_);                                     \
    float t  = piv ? -pr : f * pr;                               \
    G16C(0) G16C(1) G16C(2) G16C(3) G16C(4) G16C(5) G16C(6) G16C(7) \
    G16C(8) G16C(9) G16C(10) G16C(11) G16C(12) G16C(13) G16C(14) G16C(15) \
    e[K16_] = -t; }

__global__ __launch_bounds__(256) void gj_fprep2_k(const float* __restrict__ W,
                                                   float* __restrict__ Rnew,
                                                   unsigned short* __restrict__ RTh, unsigned short* __restrict__ RTl,
                                                   int k0){
  __shared__ float P[64][65];
  __shared__ float Rt[16][68];
  __shared__ float S[64][68];
  int b = blockIdx.x;
  int J = blockIdx.y * 64;
  int tid = threadIdx.x;
  int l = tid & 63, w = tid >> 6;
  int q16 = w << 4;
  int mm = l & 15;
  const float* Wr = W + (long)b * 1048576 + (long)k0 * 1024 + J;
  for (int i = tid; i < 1024; i += 256) {
    int q = i >> 4, j4 = (i & 15) << 2;
    *(float4*)&S[q][j4] = ld4(Wr + (long)q * 1024 + j4);
  }
  const float* Wd = W + (long)b * 1048576 + (long)(k0 + l) * 1024 + k0 + q16;
#pragma unroll
  for (int c = 0; c < 16; c += 4) {
    float4 v = ld4(Wd + c);
    P[l][q16 + c] = v.x; P[l][q16 + c + 1] = v.y;
    P[l][q16 + c + 2] = v.z; P[l][q16 + c + 3] = v.w;
  }
  __syncthreads();
  for (int kb = 0; kb < 4; ++kb) {
    int kbase = kb << 4;
    float e[16];
#pragma unroll
    for (int c = 0; c < 16; ++c) e[c] = P[kbase + mm][kbase + c];
    G16S(0) G16S(1) G16S(2) G16S(3) G16S(4) G16S(5) G16S(6) G16S(7)
    G16S(8) G16S(9) G16S(10) G16S(11) G16S(12) G16S(13) G16S(14) G16S(15)
    float Cc[16];
#pragma unroll
    for (int c = 0; c < 16; ++c) Cc[c] = P[l][kbase + c];
    int c4 = q16 + ((l >> 4) << 2);
    float r0, r1, r2, r3;
    if (w == kb) {
      int g = l >> 4;
      if (g == 0)      { r0 = e[0];  r1 = e[1];  r2 = e[2];  r3 = e[3];  }
      else if (g == 1) { r0 = e[4];  r1 = e[5];  r2 = e[6];  r3 = e[7];  }
      else if (g == 2) { r0 = e[8];  r1 = e[9];  r2 = e[10]; r3 = e[11]; }
      else             { r0 = e[12]; r1 = e[13]; r2 = e[14]; r3 = e[15]; }
    } else {
      r0 = r1 = r2 = r3 = 0.f;
#pragma unroll
      for (int j = 0; j < 16; ++j) {
        float ej = e[j];
        r0 = fmaf(ej, P[kbase + j][c4 + 0], r0);
        r1 = fmaf(ej, P[kbase + j][c4 + 1], r1);
        r2 = fmaf(ej, P[kbase + j][c4 + 2], r2);
        r3 = fmaf(ej, P[kbase + j][c4 + 3], r3);
      }
    }
    Rt[mm][c4 + 0] = r0; Rt[mm][c4 + 1] = r1;
    Rt[mm][c4 + 2] = r2; Rt[mm][c4 + 3] = r3;
    __syncthreads();
    if (l >= kbase && l < kbase + 16) {
#pragma unroll
      for (int c = 0; c < 16; c += 4) {
        float4 v = *(float4*)&Rt[l - kbase][q16 + c];
        P[l][q16 + c] = v.x; P[l][q16 + c + 1] = v.y;
        P[l][q16 + c + 2] = v.z; P[l][q16 + c + 3] = v.w;
      }
    } else {
      float acc[16];
      bool colKb = (w == kb);
#pragma unroll
      for (int c = 0; c < 16; ++c) acc[c] = colKb ? 0.f : P[l][q16 + c];
#pragma unroll
      for (int j = 0; j < 16; ++j) {
        float cj = Cc[j];
        float4 v0 = *(float4*)&Rt[j][q16 + 0];
        float4 v1 = *(float4*)&Rt[j][q16 + 4];
        float4 v2 = *(float4*)&Rt[j][q16 + 8];
        float4 v3 = *(float4*)&Rt[j][q16 + 12];
        acc[0]  = fmaf(-cj, v0.x, acc[0]);  acc[1]  = fmaf(-cj, v0.y, acc[1]);
        acc[2]  = fmaf(-cj, v0.z, acc[2]);  acc[3]  = fmaf(-cj, v0.w, acc[3]);
        acc[4]  = fmaf(-cj, v1.x, acc[4]);  acc[5]  = fmaf(-cj, v1.y, acc[5]);
        acc[6]  = fmaf(-cj, v1.z, acc[6]);  acc[7]  = fmaf(-cj, v1.w, acc[7]);
        acc[8]  = fmaf(-cj, v2.x, acc[8]);  acc[9]  = fmaf(-cj, v2.y, acc[9]);
        acc[10] = fmaf(-cj, v2.z, acc[10]); acc[11] = fmaf(-cj, v2.w, acc[11]);
        acc[12] = fmaf(-cj, v3.x, acc[12]); acc[13] = fmaf(-cj, v3.y, acc[13]);
        acc[14] = fmaf(-cj, v3.z, acc[14]); acc[15] = fmaf(-cj, v3.w, acc[15]);
      }
#pragma unroll
      for (int c = 0; c < 16; ++c) P[l][q16 + c] = acc[c];
    }
    __syncthreads();
  }
  int p = tid & 63;
  float acc2[16] = {};
  for (int q = 0; q < 64; ++q) {
    float d = P[p][q];
#pragma unroll
    for (int c = 0; c < 16; ++c) acc2[c] = fmaf(d, S[q][q16 + c], acc2[c]);
  }
  __syncthreads();
#pragma unroll
  for (int c = 0; c < 16; ++c) {
    int jg = J + q16 + c;
    float v = acc2[c];
    if (jg >= k0 && jg < k0 + 64) v = P[p][jg - k0];
    S[p][q16 + c] = v;
  }
  __syncthreads();
  float* Rb = Rnew + (long)b * 65536 + J;
  for (int i = tid; i < 1024; i += 256) {
    int rr = i >> 4, j4 = (i & 15) << 2;
    *(float4*)(Rb + (long)rr * 1024 + j4) = *(float4*)&S[rr][j4];
  }
  unsigned short* th = RTh + (long)b * 65536 + (long)J * 64;
  unsigned short* tl = RTl + (long)b * 65536 + (long)J * 64;
  for (int i = tid; i < 4096; i += 256) {
    int jl = i >> 6, pp = i & 63;
    float v = S[pp][jl];
    unsigned short h = bf16rne(v);
    float hf = __uint_as_float((unsigned)h << 16);
    th[i] = h;
    tl[i] = bf16rne(v - hf);
  }
}

// ---------------- GJ trailing update: 64x64 tiles, bf16x3 MFMA, global-direct fragments ----------------
__global__ __launch_bounds__(256) void gupd_k(const unsigned short* __restrict__ Ch, const unsigned short* __restrict__ Cl,
                                              const unsigned short* __restrict__ RTh, const unsigned short* __restrict__ RTl,
                                              const float* __restrict__ Rnew, float* __restrict__ W,
                                              unsigned short* __restrict__ ChN, unsigned short* __restrict__ ClN, int k0){
  int b = blockIdx.x;
  const unsigned short* Ahp = Ch + (long)b * 65536;
  const unsigned short* Alp = Cl + (long)b * 65536;
  const unsigned short* Bhp = RTh + (long)b * 65536;
  const unsigned short* Blp = RTl + (long)b * 65536;
  const float* Rb = Rnew + (long)b * 65536;
  float* Wb = W + (long)b * 1048576;
  unsigned short* CnH = ChN + (long)b * 65536;
  unsigned short* CnL = ClN + (long)b * 65536;
  const int tid = threadIdx.x, l = tid & 63, wid = tid >> 6;
  const int wr = wid >> 1, wc = wid & 1;
  const int m0 = blockIdx.y * 64, n0 = blockIdx.z * 64;
  const int lrow = l & 15, kc8 = (l >> 4) << 3;
  f32x4 acc[2][2] = {};
#pragma unroll
  for (int kk = 0; kk < 2; ++kk) {
    bf16x8 ah[2], al4[2], bh[2], bl4[2];
#pragma unroll
    for (int t = 0; t < 2; ++t) {
      int ra = m0 + wr * 32 + t * 16 + lrow;
      long offa = (long)ra * 64 + kk * 32 + kc8;
      ah[t]  = *(const bf16x8*)(Ahp + offa);
      al4[t] = *(const bf16x8*)(Alp + offa);
      int rb = n0 + wc * 32 + t * 16 + lrow;
      long offb = (long)rb * 64 + kk * 32 + kc8;
      bh[t]  = *(const bf16x8*)(Bhp + offb);
      bl4[t] = *(const bf16x8*)(Blp + offb);
    }
#pragma unroll
    for (int mi = 0; mi < 2; ++mi)
#pragma unroll
      for (int ni = 0; ni < 2; ++ni) {
        acc[mi][ni] = __builtin_amdgcn_mfma_f32_16x16x32_bf16(ah[mi],  bh[ni],  acc[mi][ni], 0, 0, 0);
        acc[mi][ni] = __builtin_amdgcn_mfma_f32_16x16x32_bf16(ah[mi],  bl4[ni], acc[mi][ni], 0, 0, 0);
        acc[mi][ni] = __builtin_amdgcn_mfma_f32_16x16x32_bf16(al4[mi], bh[ni],  acc[mi][ni], 0, 0, 0);
      }
  }
#pragma unroll
  for (int mi = 0; mi < 2; ++mi)
#pragma unroll
  for (int ni = 0; ni < 2; ++ni)
#pragma unroll
  for (int r = 0; r < 4; ++r) {
    int m = m0 + wr * 32 + mi * 16 + ((l >> 4) << 2) + r;
    int n = n0 + wc * 32 + ni * 16 + (l & 15);
    bool rowK = (m >= k0 && m < k0 + 64);
    bool colK = (n >= k0 && n < k0 + 64);
    float v;
    if (rowK)      v = Rb[(long)(m - k0) * 1024 + n];
    else if (colK) v = -acc[mi][ni][r];
    else           v = Wb[(long)m * 1024 + n] - acc[mi][ni][r];
    Wb[(long)m * 1024 + n] = v;
    int cn = n - k0 - 64;
    if (cn >= 0 && cn < 64) {
      unsigned short h = bf16rne(v);
      float hf = __uint_as_float((unsigned)h << 16);
      CnH[(long)m * 64 + cn] = h;
      CnL[(long)m * 64 + cn] = bf16rne(v - hf);
    }
  }
}

// ---------------- d0, diag, df col 0 ----------------
__global__ void ddiag_k(const float* __restrict__ W, const float* __restrict__ fi,
                        float* __restrict__ d0, float* __restrict__ diag, float* __restrict__ dfout){
  int t = blockIdx.x * 256 + threadIdx.x;
  int b = t >> 10, i = t & 1023;
  const float* Wb = W + (long)b * TT * TT;
  float dv = fi[t] * Wb[(long)i * TT];
  d0[t] = dv;
  diag[t] = Wb[(long)i * TT + i];
  dfout[(long)b * TT * 1025 + (long)i * 1025] = dv;
}

// ---------------- dx: compute, emit bf16 dx + bf16 dx^T + df store ----------------
__global__ __launch_bounds__(256) void dx_k(const float* __restrict__ A, const float* __restrict__ W,
                                            const float* __restrict__ diag, float* __restrict__ dfout,
                                            unsigned short* __restrict__ dxb, unsigned short* __restrict__ dxTb){
  int b = blockIdx.z;
  int i0 = blockIdx.y * 64, j0 = blockIdx.x * 64;
  const float* Wb = W + (long)b * TT * TT;
  const float* Ab = A + (long)b * TT * TT;
  __shared__ float Ls[64][65];
  __shared__ float Sx[64][65];
  int tid = threadIdx.x;
  for (int idx = tid; idx < 4096; idx += 256) {
    int r = idx >> 6, c = idx & 63;
    Ls[r][c] = Wb[(long)(j0 + r) * TT + i0 + c];
  }
  __syncthreads();
  for (int idx = tid; idx < 4096; idx += 256) {
    int r = idx >> 6, c = idx & 63;
    int i = i0 + r, j = j0 + c;
    float a = Ab[(long)i * TT + j];
    float v = 0.f;
    if (j > 0) v = a * diag[b * TT + j];
    if (i > 0) v -= a * Ls[c][r];
    dxb[(long)b * 1048576 + (long)i * 1024 + j] = bf16rne(v);
    Sx[r][c] = v;
  }
  __syncthreads();
  float* dfb = dfout + (long)b * TT * 1025;
  unsigned short* dtb = dxTb + (long)b * 1048576;
  for (int idx = tid; idx < 4096; idx += 256) {
    int r = idx >> 6, c = idx & 63;
    float v = Sx[c][r];
    dfb[(long)(j0 + r) * 1025 + i0 + 1 + c] = v;
    dtb[(long)(j0 + r) * 1024 + i0 + c] = bf16rne(v);
  }
}

extern "C" void kernel_launch(void* const* d_in, const int* in_sizes, int n_in,
                              void* d_out, int out_size, void* d_ws, size_t ws_size,
                              hipStream_t stream){
  const float* input   = (const float*)d_in[0];
  const float* Wtp     = (const float*)d_in[1];
  const float* btp     = (const float*)d_in[2];
  const float* Wtc     = (const float*)d_in[3];
  const float* btc     = (const float*)d_in[4];
  const float* wfi     = (const float*)d_in[5];
  const float* Wbil    = (const float*)d_in[6];
  const float* exparam = (const float*)d_in[7];
  const float* Wfz     = (const float*)d_in[8];
  const float* bfz     = (const float*)d_in[9];

  if (ws_size < 147000000UL) return;

  float* ws   = (float*)d_ws;
  float* sem   = ws;                    // 4,194,304 f
  float* strv  = ws + 4194304;          // 4,194,304 f  [later: dxb bf16]
  float* Abuf  = ws + 8388608;          // 8,388,608 f  [later: finpb bf16]
  float* Wbuf  = ws + 16777216;         // 8,388,608 f
  unsigned short* strb = (unsigned short*)(ws + 25165824);
  unsigned short* tpb  = (unsigned short*)(ws + 27262976);
  unsigned short* tcb  = (unsigned short*)(ws + 29360128);
  unsigned short* tpwb = (unsigned short*)(ws + 31457280);
  unsigned short* wtpb = (unsigned short*)(ws + 33554432);
  unsigned short* wtcb = (unsigned short*)(ws + 33685504);
  unsigned short* wbilT= (unsigned short*)(ws + 33816576);
  unsigned short* wfzb = (unsigned short*)(ws + 33947648);
  float* fi    = ws + 34340864;         // 8192
  float* csp   = ws + 34349056;         // 131,072
  float* d0    = ws + 34480128;         // 8192
  float* dg    = ws + 34488320;         // 8192
  float* Rnew  = ws + 34496512;         // 524,288
  unsigned short* ChA = (unsigned short*)(ws + 35020800);
  unsigned short* ClA = (unsigned short*)(ws + 35282944);
  unsigned short* ChB = (unsigned short*)(ws + 35545088);
  unsigned short* ClB = (unsigned short*)(ws + 35807232);
  unsigned short* RTh = (unsigned short*)(ws + 36069376);
  unsigned short* RTl = (unsigned short*)(ws + 36331520);
  unsigned short* dxb   = (unsigned short*)strv;
  unsigned short* dxTb  = (unsigned short*)(ws + 25165824);
  unsigned short* semTb = (unsigned short*)(ws + 29360128);
  unsigned short* finpb = (unsigned short*)Abuf;

  float* outp = (float*)d_out;
  float* dfp  = outp + 4194304;

  split_k<<<8192, 256, 0, stream>>>(input, sem, strv, strb, wfi, fi);
  castmisc_k<<<1536, 256, 0, stream>>>(Wtp, Wtc, Wfz, Wbil, wtpb, wtcb, wfzb, wbilT);
  mgemm_k<1,1><<<dim3(4,128,1),256,0,stream>>>(strb, wtpb, tpb, 512, 512, 512, 512, 0,0,0, btp, nullptr,0,nullptr);
  mgemm_k<1,1><<<dim3(4,128,1),256,0,stream>>>(strb, wtcb, tcb, 512, 512, 512, 512, 0,0,0, btc, nullptr,0,nullptr);
  mgemm_k<0,1><<<dim3(4,128,1),256,0,stream>>>(tpb, wbilT, tpwb, 512, 512, 512, 512, 0,0,0, nullptr, nullptr,0,nullptr);
  mgemm_score_k<<<dim3(8,16,8),256,0,stream>>>(tpwb, tcb, Abuf, Wbuf, csp);
  castT_k<<<dim3(16,32,8), 256, 0, stream>>>(sem, semTb, 1024, 512, 524288, 524288);
  buildfix_k<<<dim3(16,8),256,0,stream>>>(csp, fi, Wbuf, ChA, ClA);
  for (int s = 0; s < 16; ++s) {
    int k0 = s * NB;
    unsigned short* ChI = (s & 1) ? ChB : ChA;
    unsigned short* ClI = (s & 1) ? ClB : ClA;
    unsigned short* ChO = (s & 1) ? ChA : ChB;
    unsigned short* ClO = (s & 1) ? ClA : ClB;
    gj_fprep2_k<<<dim3(8,16),256,0,stream>>>(Wbuf, Rnew, RTh, RTl, k0);
    gupd_k<<<dim3(8,16,16),256,0,stream>>>(ChI, ClI, RTh, RTl, Rnew, Wbuf, ChO, ClO, k0);
  }
  ddiag_k<<<32,256,0,stream>>>(Wbuf, fi, d0, dg, dfp);
  dx_k<<<dim3(16,16,8),256,0,stream>>>(Abuf, Wbuf, dg, dfp, dxb, dxTb);
  semcopy_k<<<4096,256,0,stream>>>(sem, finpb);
  mgemm_pc_k<<<dim3(4,16,16),256,0,stream>>>(dxTb, dxb, semTb, finpb + 512, finpb + 1024,
                                             1024, 1024, 1024, 1536, 1048576, 524288, 1572864,
                                             d0, 1024, exparam);
  mgemm_k<3,0><<<dim3(4,128,1),256,0,stream>>>(finpb, wfzb, outp, 1536, 1536, 1536, 512, 0,0,0, bfz, nullptr,0,nullptr);
}

// Round 20
// 1016.465 us; speedup vs baseline: 1.1773x; 1.0003x over previous
//
#include <hip/hip_runtime.h>
#include <math.h>

#define TT 1024
#define NB 64

typedef float f32x4 __attribute__((ext_vector_type(4)));
typedef __bf16 bf16x8 __attribute__((ext_vector_type(8)));

__device__ __forceinline__ float4 ld4(const float* p){ return *(const float4*)p; }
__device__ __forceinline__ float rdlane(float v, int lane){
  return __int_as_float(__builtin_amdgcn_readlane(__float_as_int(v), lane));
}
__device__ __forceinline__ unsigned short bf16rne(float x){
  unsigned u = __float_as_uint(x);
  return (unsigned short)((u + 0x7FFF + ((u >> 16) & 1)) >> 16);
}

// ================= bf16 MFMA GEMM: C = epi(A @ B^T_panels), 64x128 tile =================
template<int EPI, int OUTBF>
__global__ __launch_bounds__(256)
void mgemm_k(const unsigned short* __restrict__ A, const unsigned short* __restrict__ B,
             void* __restrict__ Cv, int K, int lda, int ldb, int ldc,
             long sA, long sB, long sC,
             const float* __restrict__ bias,
             const float* __restrict__ e1, long sE1, const float* __restrict__ e2)
{
  const int bz = blockIdx.z;
  A += (long)bz * sA; B += (long)bz * sB;
  __shared__ char lds[12288];
  char* As = lds;
  char* Bs = lds + 4096;
  const int tid = threadIdx.x;
  const int l = tid & 63, wid = tid >> 6;
  const int wr = wid >> 1, wc = wid & 1;
  const int m0 = blockIdx.y * 64, n0 = blockIdx.x * 128;
  const int lrow = l & 15, lslot = (l >> 4) << 4;
  f32x4 acc[2][4] = {};

  for (int kk = 0; kk < K; kk += 32) {
    {
      int row = tid >> 2, c16 = (tid & 3) << 4;
      int sw = c16 ^ (((row >> 1) & 3) << 4);
      uint4 va = *(const uint4*)(A + (long)(m0 + row) * lda + kk + (c16 >> 1));
      *(uint4*)(As + row * 64 + sw) = va;
    }
#pragma unroll
    for (int i = 0; i < 2; ++i) {
      int idx = i * 256 + tid;
      int row = idx >> 2, c16 = (idx & 3) << 4;
      int sw = c16 ^ (((row >> 1) & 3) << 4);
      uint4 vb = *(const uint4*)(B + (long)(n0 + row) * ldb + kk + (c16 >> 1));
      *(uint4*)(Bs + row * 64 + sw) = vb;
    }
    __syncthreads();
    bf16x8 af[2], bfr[4];
#pragma unroll
    for (int t = 0; t < 2; ++t) {
      int ra = wr * 32 + t * 16 + lrow;
      af[t]  = *(const bf16x8*)(As + ra * 64 + (lslot ^ (((ra >> 1) & 3) << 4)));
    }
#pragma unroll
    for (int t = 0; t < 4; ++t) {
      int rb = wc * 64 + t * 16 + lrow;
      bfr[t] = *(const bf16x8*)(Bs + rb * 64 + (lslot ^ (((rb >> 1) & 3) << 4)));
    }
#pragma unroll
    for (int mi = 0; mi < 2; ++mi)
#pragma unroll
      for (int ni = 0; ni < 4; ++ni)
        acc[mi][ni] = __builtin_amdgcn_mfma_f32_16x16x32_bf16(af[mi], bfr[ni], acc[mi][ni], 0, 0, 0);
    __syncthreads();
  }

  float* Cf = (float*)Cv; unsigned short* Cb = (unsigned short*)Cv;
  if (OUTBF) Cb += (long)bz * sC; else Cf += (long)bz * sC;
  if (e1) e1 += (long)bz * sE1;
#pragma unroll
  for (int mi = 0; mi < 2; ++mi)
#pragma unroll
  for (int ni = 0; ni < 4; ++ni)
#pragma unroll
  for (int r = 0; r < 4; ++r) {
    int m = m0 + wr * 32 + mi * 16 + ((l >> 4) << 2) + r;
    int n = n0 + wc * 64 + ni * 16 + (l & 15);
    float v = acc[mi][ni][r];
    if (EPI == 1) v = tanhf(v + bias[n]);
    else if (EPI == 3) v = fmaxf(v + bias[n], 0.f);
    else if (EPI == 4) v = v + e1[m] * e2[n];
    if (OUTBF) Cb[(long)m * ldc + n] = bf16rne(v);
    else       Cf[(long)m * ldc + n] = v;
  }
}

// ===== A-score GEMM: A = exp(tanh(tpw@tc^T)) zero-diag; emits A, W=-A, colsum partials =====
__global__ __launch_bounds__(256)
void mgemm_score_k(const unsigned short* __restrict__ A, const unsigned short* __restrict__ B,
                   float* __restrict__ Ab, float* __restrict__ Wb, float* __restrict__ csp)
{
  const int bz = blockIdx.z;
  A += (long)bz * 524288; B += (long)bz * 524288;
  __shared__ char lds[12288];
  __shared__ float csb[2][128];
  char* As = lds; char* Bs = lds + 4096;
  const int tid = threadIdx.x;
  const int l = tid & 63, wid = tid >> 6;
  const int wr = wid >> 1, wc = wid & 1;
  const int m0 = blockIdx.y * 64, n0 = blockIdx.x * 128;
  const int lrow = l & 15, lslot = (l >> 4) << 4;
  f32x4 acc[2][4] = {};
  for (int kk = 0; kk < 512; kk += 32) {
    {
      int row = tid >> 2, c16 = (tid & 3) << 4;
      int sw = c16 ^ (((row >> 1) & 3) << 4);
      uint4 va = *(const uint4*)(A + (long)(m0 + row) * 512 + kk + (c16 >> 1));
      *(uint4*)(As + row * 64 + sw) = va;
    }
#pragma unroll
    for (int i = 0; i < 2; ++i) {
      int idx = i * 256 + tid;
      int row = idx >> 2, c16 = (idx & 3) << 4;
      int sw = c16 ^ (((row >> 1) & 3) << 4);
      uint4 vb = *(const uint4*)(B + (long)(n0 + row) * 512 + kk + (c16 >> 1));
      *(uint4*)(Bs + row * 64 + sw) = vb;
    }
    __syncthreads();
    bf16x8 af[2], bfr[4];
#pragma unroll
    for (int t = 0; t < 2; ++t) {
      int ra = wr * 32 + t * 16 + lrow;
      af[t]  = *(const bf16x8*)(As + ra * 64 + (lslot ^ (((ra >> 1) & 3) << 4)));
    }
#pragma unroll
    for (int t = 0; t < 4; ++t) {
      int rb = wc * 64 + t * 16 + lrow;
      bfr[t] = *(const bf16x8*)(Bs + rb * 64 + (lslot ^ (((rb >> 1) & 3) << 4)));
    }
#pragma unroll
    for (int mi = 0; mi < 2; ++mi)
#pragma unroll
      for (int ni = 0; ni < 4; ++ni)
        acc[mi][ni] = __builtin_amdgcn_mfma_f32_16x16x32_bf16(af[mi], bfr[ni], acc[mi][ni], 0, 0, 0);
    __syncthreads();
  }
  Ab += (long)bz * 1048576; Wb += (long)bz * 1048576;
  float cst[4] = {0.f, 0.f, 0.f, 0.f};
#pragma unroll
  for (int mi = 0; mi < 2; ++mi)
#pragma unroll
  for (int ni = 0; ni < 4; ++ni)
#pragma unroll
  for (int r = 0; r < 4; ++r) {
    int m = m0 + wr * 32 + mi * 16 + ((l >> 4) << 2) + r;
    int n = n0 + wc * 64 + ni * 16 + (l & 15);
    float v = (m == n) ? 0.f : expf(tanhf(acc[mi][ni][r]));
    Ab[(long)m * 1024 + n] = v;
    Wb[(long)m * 1024 + n] = -v;
    cst[ni] += v;
  }
#pragma unroll
  for (int ni = 0; ni < 4; ++ni) {
    cst[ni] += __shfl_xor(cst[ni], 16, 64);
    cst[ni] += __shfl_xor(cst[ni], 32, 64);
  }
  if ((l >> 4) == 0) {
#pragma unroll
    for (int ni = 0; ni < 4; ++ni) csb[wr][wc * 64 + ni * 16 + (l & 15)] = cst[ni];
  }
  __syncthreads();
  if (tid < 128)
    csp[(long)blockIdx.y * 8192 + bz * 1024 + n0 + tid] = csb[0][tid] + csb[1][tid];
}

// ========== dual-output variant for pinp / cinp, 64x128 tile, bf16 out ==========
__global__ __launch_bounds__(256)
void mgemm_pc_k(const unsigned short* __restrict__ A1, const unsigned short* __restrict__ A2,
                const unsigned short* __restrict__ B,
                unsigned short* __restrict__ C1, unsigned short* __restrict__ C2,
                int K, int lda, int ldb, int ldc, long sA, long sB, long sC,
                const float* __restrict__ e1, long sE1, const float* __restrict__ e2)
{
  const int z = blockIdx.z;
  const int bz = z & 7;
  const bool second = (z >= 8);
  const unsigned short* A = (second ? A2 : A1) + (long)bz * sA;
  const unsigned short* Bp = B + (long)bz * sB;
  unsigned short* C = (second ? C2 : C1) + (long)bz * sC;
  const float* e1p = second ? nullptr : (e1 + (long)bz * sE1);
  __shared__ char lds[12288];
  char* As = lds; char* Bs = lds + 4096;
  const int tid = threadIdx.x;
  const int l = tid & 63, wid = tid >> 6;
  const int wr = wid >> 1, wc = wid & 1;
  const int m0 = blockIdx.y * 64, n0 = blockIdx.x * 128;
  const int lrow = l & 15, lslot = (l >> 4) << 4;
  f32x4 acc[2][4] = {};
  for (int kk = 0; kk < K; kk += 32) {
    {
      int row = tid >> 2, c16 = (tid & 3) << 4;
      int sw = c16 ^ (((row >> 1) & 3) << 4);
      uint4 va = *(const uint4*)(A + (long)(m0 + row) * lda + kk + (c16 >> 1));
      *(uint4*)(As + row * 64 + sw) = va;
    }
#pragma unroll
    for (int i = 0; i < 2; ++i) {
      int idx = i * 256 + tid;
      int row = idx >> 2, c16 = (idx & 3) << 4;
      int sw = c16 ^ (((row >> 1) & 3) << 4);
      uint4 vb = *(const uint4*)(Bp + (long)(n0 + row) * ldb + kk + (c16 >> 1));
      *(uint4*)(Bs + row * 64 + sw) = vb;
    }
    __syncthreads();
    bf16x8 af[2], bfr[4];
#pragma unroll
    for (int t = 0; t < 2; ++t) {
      int ra = wr * 32 + t * 16 + lrow;
      af[t]  = *(const bf16x8*)(As + ra * 64 + (lslot ^ (((ra >> 1) & 3) << 4)));
    }
#pragma unroll
    for (int t = 0; t < 4; ++t) {
      int rb = wc * 64 + t * 16 + lrow;
      bfr[t] = *(const bf16x8*)(Bs + rb * 64 + (lslot ^ (((rb >> 1) & 3) << 4)));
    }
#pragma unroll
    for (int mi = 0; mi < 2; ++mi)
#pragma unroll
      for (int ni = 0; ni < 4; ++ni)
        acc[mi][ni] = __builtin_amdgcn_mfma_f32_16x16x32_bf16(af[mi], bfr[ni], acc[mi][ni], 0, 0, 0);
    __syncthreads();
  }
#pragma unroll
  for (int mi = 0; mi < 2; ++mi)
#pragma unroll
  for (int ni = 0; ni < 4; ++ni)
#pragma unroll
  for (int r = 0; r < 4; ++r) {
    int m = m0 + wr * 32 + mi * 16 + ((l >> 4) << 2) + r;
    int n = n0 + wc * 64 + ni * 16 + (l & 15);
    float v = acc[mi][ni][r];
    if (e1p) v = v + e1p[m] * e2[n];
    C[(long)m * ldc + n] = bf16rne(v);
  }
}

// ---------------- feature split (+ strb bf16 emit + fused fi) ----------------
__global__ void split_k(const float* __restrict__ in, float* __restrict__ sem,
                        float* __restrict__ str, unsigned short* __restrict__ strb,
                        const float* __restrict__ wfi, float* __restrict__ fi){
  __shared__ float red[4];
  long row = blockIdx.x;
  int c = threadIdx.x << 2;
  float4 v = ld4(in + row * 1024 + c);
  bool isStr = (c >= 256 && c < 512) || (c >= 768);
  int off;
  float* dst;
  if (c < 256)      { dst = sem + row * 512 + c;               off = c; }
  else if (c < 512) { dst = str + row * 512 + (c - 256);       off = c - 256; }
  else if (c < 768) { dst = sem + row * 512 + 256 + (c - 512); off = 0; }
  else              { dst = str + row * 512 + 256 + (c - 768); off = 256 + (c - 768); }
  *(float4*)dst = v;
  float d = 0.f;
  if (isStr) {
    unsigned lo = bf16rne(v.x) | ((unsigned)bf16rne(v.y) << 16);
    unsigned hi = bf16rne(v.z) | ((unsigned)bf16rne(v.w) << 16);
    uint2 w; w.x = lo; w.y = hi;
    *(uint2*)(strb + row * 512 + off) = w;
    d = v.x * wfi[off] + v.y * wfi[off + 1] + v.z * wfi[off + 2] + v.w * wfi[off + 3];
  }
#pragma unroll
  for (int o = 32; o; o >>= 1) d += __shfl_down(d, o, 64);
  int lane = threadIdx.x & 63, wv = threadIdx.x >> 6;
  if (lane == 0) red[wv] = d;
  __syncthreads();
  if (threadIdx.x == 0)
    fi[row] = expf(tanhf(red[0] + red[1] + red[2] + red[3]));
}

// ---------------- merged weight casts ----------------
__global__ __launch_bounds__(256) void castmisc_k(const float* __restrict__ Wtp, const float* __restrict__ Wtc,
                                                  const float* __restrict__ Wfz, const float* __restrict__ Wbil,
                                                  unsigned short* __restrict__ wtpb, unsigned short* __restrict__ wtcb,
                                                  unsigned short* __restrict__ wfzb, unsigned short* __restrict__ wbilT){
  __shared__ float t[32][33];
  int bx = blockIdx.x;
  if (bx < 1280) {
    long i = ((long)bx * 256 + threadIdx.x) << 2;
    const float* src; unsigned short* dst; long off;
    if (i < 262144)      { src = Wtp; dst = wtpb; off = i; }
    else if (i < 524288) { src = Wtc; dst = wtcb; off = i - 262144; }
    else                 { src = Wfz; dst = wfzb; off = i - 524288; }
    float4 v = ld4(src + off);
    unsigned lo = bf16rne(v.x) | ((unsigned)bf16rne(v.y) << 16);
    unsigned hi = bf16rne(v.z) | ((unsigned)bf16rne(v.w) << 16);
    uint2 w; w.x = lo; w.y = hi;
    *(uint2*)(dst + off) = w;
  } else {
    int id = bx - 1280;
    int r0 = (id >> 4) * 32, c0 = (id & 15) * 32;
    int tx = threadIdx.x & 31, ty = threadIdx.x >> 5;
#pragma unroll
    for (int j = 0; j < 32; j += 8)
      t[ty + j][tx] = Wbil[(long)(r0 + ty + j) * 512 + c0 + tx];
    __syncthreads();
#pragma unroll
    for (int j = 0; j < 32; j += 8)
      wbilT[(long)(c0 + ty + j) * 512 + r0 + tx] = bf16rne(t[tx][ty + j]);
  }
}

__global__ __launch_bounds__(256) void castT_k(const float* __restrict__ src, unsigned short* __restrict__ dst,
                                               int R, int C, long sS, long sD){
  int b = blockIdx.z;
  src += (long)b * sS; dst += (long)b * sD;
  __shared__ float t[32][33];
  int r0 = blockIdx.y * 32, c0 = blockIdx.x * 32;
  int tx = threadIdx.x & 31, ty = threadIdx.x >> 5;
#pragma unroll
  for (int j = 0; j < 32; j += 8)
    t[ty + j][tx] = src[(long)(r0 + ty + j) * C + c0 + tx];
  __syncthreads();
#pragma unroll
  for (int j = 0; j < 32; j += 8)
    dst[(long)(c0 + ty + j) * R + r0 + tx] = bf16rne(t[tx][ty + j]);
}

__global__ void semcopy_k(const float* __restrict__ sem, unsigned short* __restrict__ finpb){
  long idx = ((long)blockIdx.x * 256 + threadIdx.x) << 2;
  long row = idx >> 9; int col = (int)(idx & 511);
  float4 v = ld4(sem + idx);
  unsigned lo = bf16rne(v.x) | ((unsigned)bf16rne(v.y) << 16);
  unsigned hi = bf16rne(v.z) | ((unsigned)bf16rne(v.w) << 16);
  uint2 w; w.x = lo; w.y = hi;
  *(uint2*)(finpb + row * 1536 + col) = w;
}

// ---------------- buildfix: W row0=fi, diag=colsum; emit Cold0 hi/lo ----------------
__global__ void buildfix_k(const float* __restrict__ csp, const float* __restrict__ fi,
                           float* __restrict__ W,
                           unsigned short* __restrict__ Ch0, unsigned short* __restrict__ Cl0){
  int rc = blockIdx.x, b = blockIdx.y;
  int tid = threadIdx.x;
  __shared__ float cs[64];
  int i0 = rc * 64;
  if (tid < 64) {
    float s = 0.f;
#pragma unroll
    for (int p = 0; p < 16; ++p) s += csp[(long)p * 8192 + b * 1024 + i0 + tid];
    cs[tid] = s;
  }
  __syncthreads();
  float* Wb = W + (long)b * 1048576;
  const float* fib = fi + b * 1024;
  if (rc == 0) {
    for (int j = tid; j < 1024; j += 256) Wb[j] = fib[j];
  }
  if (tid < 64) {
    int i = i0 + tid;
    if (i != 0) Wb[(long)i * 1024 + i] = cs[tid];
  }
  unsigned short* ChB_ = Ch0 + b * 65536;
  unsigned short* ClB_ = Cl0 + b * 65536;
  for (int e = tid; e < 4096; e += 256) {
    int ii = e >> 6, j = e & 63;
    int i = i0 + ii;
    float v;
    if (i == 0)      v = fib[j];
    else if (i == j) v = cs[ii];
    else             v = Wb[(long)i * 1024 + j];
    unsigned short h = bf16rne(v);
    float hf = __uint_as_float((unsigned)h << 16);
    ChB_[(long)i * 64 + j] = h;
    ClB_[(long)i * 64 + j] = bf16rne(v - hf);
  }
}

// ---------------- GJ fused: {two-level 64x64 diag inverse in LDS} + {Rnew 64-col chunk} ----------------
#define G16C(c) { float bc = rdlane(e[(c)], K16_);               \
                  float z  = piv ? 0.f : e[(c)];                 \
                  e[(c)] = fmaf(-t, bc, z); }
#define G16S(k) { enum { K16_ = (k) };                           \
    float pk = rdlane(e[K16_], K16_);                            \
    float pr = 1.f / pk;                                         \
    float f  = e[K16_];                                          \
    bool piv = (mm == K16_);                                     \
    float t  = piv ? -pr : f * pr;                               \
    G16C(0) G16C(1) G16C(2) G16C(3) G16C(4) G16C(5) G16C(6) G16C(7) \
    G16C(8) G16C(9) G16C(10) G16C(11) G16C(12) G16C(13) G16C(14) G16C(15) \
    e[K16_] = -t; }

__global__ __launch_bounds__(256) void gj_fprep2_k(const float* __restrict__ W,
                                                   float* __restrict__ Rnew,
                                                   unsigned short* __restrict__ RTh, unsigned short* __restrict__ RTl,
                                                   int k0){
  __shared__ float P[64][65];
  __shared__ float Rt[16][68];
  __shared__ float S[64][68];
  int b = blockIdx.x;
  int J = blockIdx.y * 64;
  int tid = threadIdx.x;
  int l = tid & 63, w = tid >> 6;
  int q16 = w << 4;
  int mm = l & 15;
  const float* Wr = W + (long)b * 1048576 + (long)k0 * 1024 + J;
  for (int i = tid; i < 1024; i += 256) {
    int q = i >> 4, j4 = (i & 15) << 2;
    *(float4*)&S[q][j4] = ld4(Wr + (long)q * 1024 + j4);
  }
  const float* Wd = W + (long)b * 1048576 + (long)(k0 + l) * 1024 + k0 + q16;
#pragma unroll
  for (int c = 0; c < 16; c += 4) {
    float4 v = ld4(Wd + c);
    P[l][q16 + c] = v.x; P[l][q16 + c + 1] = v.y;
    P[l][q16 + c + 2] = v.z; P[l][q16 + c + 3] = v.w;
  }
  __syncthreads();
  for (int kb = 0; kb < 4; ++kb) {
    int kbase = kb << 4;
    float e[16];
#pragma unroll
    for (int c = 0; c < 16; ++c) e[c] = P[kbase + mm][kbase + c];
    G16S(0) G16S(1) G16S(2) G16S(3) G16S(4) G16S(5) G16S(6) G16S(7)
    G16S(8) G16S(9) G16S(10) G16S(11) G16S(12) G16S(13) G16S(14) G16S(15)
    float Cc[16];
#pragma unroll
    for (int c = 0; c < 16; ++c) Cc[c] = P[l][kbase + c];
    int c4 = q16 + ((l >> 4) << 2);
    float r0, r1, r2, r3;
    if (w == kb) {
      int g = l >> 4;
      if (g == 0)      { r0 = e[0];  r1 = e[1];  r2 = e[2];  r3 = e[3];  }
      else if (g == 1) { r0 = e[4];  r1 = e[5];  r2 = e[6];  r3 = e[7];  }
      else if (g == 2) { r0 = e[8];  r1 = e[9];  r2 = e[10]; r3 = e[11]; }
      else             { r0 = e[12]; r1 = e[13]; r2 = e[14]; r3 = e[15]; }
    } else {
      r0 = r1 = r2 = r3 = 0.f;
#pragma unroll
      for (int j = 0; j < 16; ++j) {
        float ej = e[j];
        r0 = fmaf(ej, P[kbase + j][c4 + 0], r0);
        r1 = fmaf(ej, P[kbase + j][c4 + 1], r1);
        r2 = fmaf(ej, P[kbase + j][c4 + 2], r2);
        r3 = fmaf(ej, P[kbase + j][c4 + 3], r3);
      }
    }
    Rt[mm][c4 + 0] = r0; Rt[mm][c4 + 1] = r1;
    Rt[mm][c4 + 2] = r2; Rt[mm][c4 + 3] = r3;
    __syncthreads();
    if (l >= kbase && l < kbase + 16) {
#pragma unroll
      for (int c = 0; c < 16; c += 4) {
        float4 v = *(float4*)&Rt[l - kbase][q16 + c];
        P[l][q16 + c] = v.x; P[l][q16 + c + 1] = v.y;
        P[l][q16 + c + 2] = v.z; P[l][q16 + c + 3] = v.w;
      }
    } else {
      float acc[16];
      bool colKb = (w == kb);
#pragma unroll
      for (int c = 0; c < 16; ++c) acc[c] = colKb ? 0.f : P[l][q16 + c];
#pragma unroll
      for (int j = 0; j < 16; ++j) {
        float cj = Cc[j];
        float4 v0 = *(float4*)&Rt[j][q16 + 0];
        float4 v1 = *(float4*)&Rt[j][q16 + 4];
        float4 v2 = *(float4*)&Rt[j][q16 + 8];
        float4 v3 = *(float4*)&Rt[j][q16 + 12];
        acc[0]  = fmaf(-cj, v0.x, acc[0]);  acc[1]  = fmaf(-cj, v0.y, acc[1]);
        acc[2]  = fmaf(-cj, v0.z, acc[2]);  acc[3]  = fmaf(-cj, v0.w, acc[3]);
        acc[4]  = fmaf(-cj, v1.x, acc[4]);  acc[5]  = fmaf(-cj, v1.y, acc[5]);
        acc[6]  = fmaf(-cj, v1.z, acc[6]);  acc[7]  = fmaf(-cj, v1.w, acc[7]);
        acc[8]  = fmaf(-cj, v2.x, acc[8]);  acc[9]  = fmaf(-cj, v2.y, acc[9]);
        acc[10] = fmaf(-cj, v2.z, acc[10]); acc[11] = fmaf(-cj, v2.w, acc[11]);
        acc[12] = fmaf(-cj, v3.x, acc[12]); acc[13] = fmaf(-cj, v3.y, acc[13]);
        acc[14] = fmaf(-cj, v3.z, acc[14]); acc[15] = fmaf(-cj, v3.w, acc[15]);
      }
#pragma unroll
      for (int c = 0; c < 16; ++c) P[l][q16 + c] = acc[c];
    }
    __syncthreads();
  }
  int p = tid & 63;
  float acc2[16] = {};
  for (int q = 0; q < 64; ++q) {
    float d = P[p][q];
#pragma unroll
    for (int c = 0; c < 16; ++c) acc2[c] = fmaf(d, S[q][q16 + c], acc2[c]);
  }
  __syncthreads();
#pragma unroll
  for (int c = 0; c < 16; ++c) {
    int jg = J + q16 + c;
    float v = acc2[c];
    if (jg >= k0 && jg < k0 + 64) v = P[p][jg - k0];
    S[p][q16 + c] = v;
  }
  __syncthreads();
  float* Rb = Rnew + (long)b * 65536 + J;
  for (int i = tid; i < 1024; i += 256) {
    int rr = i >> 4, j4 = (i & 15) << 2;
    *(float4*)(Rb + (long)rr * 1024 + j4) = *(float4*)&S[rr][j4];
  }
  unsigned short* th = RTh + (long)b * 65536 + (long)J * 64;
  unsigned short* tl = RTl + (long)b * 65536 + (long)J * 64;
  for (int i = tid; i < 4096; i += 256) {
    int jl = i >> 6, pp = i & 63;
    float v = S[pp][jl];
    unsigned short h = bf16rne(v);
    float hf = __uint_as_float((unsigned)h << 16);
    th[i] = h;
    tl[i] = bf16rne(v - hf);
  }
}

// ---------------- GJ trailing update: 64x64 tiles, bf16x3 MFMA, global-direct fragments ----------------
__global__ __launch_bounds__(256) void gupd_k(const unsigned short* __restrict__ Ch, const unsigned short* __restrict__ Cl,
                                              const unsigned short* __restrict__ RTh, const unsigned short* __restrict__ RTl,
                                              const float* __restrict__ Rnew, float* __restrict__ W,
                                              unsigned short* __restrict__ ChN, unsigned short* __restrict__ ClN, int k0){
  int b = blockIdx.x;
  const unsigned short* Ahp = Ch + (long)b * 65536;
  const unsigned short* Alp = Cl + (long)b * 65536;
  const unsigned short* Bhp = RTh + (long)b * 65536;
  const unsigned short* Blp = RTl + (long)b * 65536;
  const float* Rb = Rnew + (long)b * 65536;
  float* Wb = W + (long)b * 1048576;
  unsigned short* CnH = ChN + (long)b * 65536;
  unsigned short* CnL = ClN + (long)b * 65536;
  const int tid = threadIdx.x, l = tid & 63, wid = tid >> 6;
  const int wr = wid >> 1, wc = wid & 1;
  const int m0 = blockIdx.y * 64, n0 = blockIdx.z * 64;
  const int lrow = l & 15, kc8 = (l >> 4) << 3;
  f32x4 acc[2][2] = {};
#pragma unroll
  for (int kk = 0; kk < 2; ++kk) {
    bf16x8 ah[2], al4[2], bh[2], bl4[2];
#pragma unroll
    for (int t = 0; t < 2; ++t) {
      int ra = m0 + wr * 32 + t * 16 + lrow;
      long offa = (long)ra * 64 + kk * 32 + kc8;
      ah[t]  = *(const bf16x8*)(Ahp + offa);
      al4[t] = *(const bf16x8*)(Alp + offa);
      int rb = n0 + wc * 32 + t * 16 + lrow;
      long offb = (long)rb * 64 + kk * 32 + kc8;
      bh[t]  = *(const bf16x8*)(Bhp + offb);
      bl4[t] = *(const bf16x8*)(Blp + offb);
    }
#pragma unroll
    for (int mi = 0; mi < 2; ++mi)
#pragma unroll
      for (int ni = 0; ni < 2; ++ni) {
        acc[mi][ni] = __builtin_amdgcn_mfma_f32_16x16x32_bf16(ah[mi],  bh[ni],  acc[mi][ni], 0, 0, 0);
        acc[mi][ni] = __builtin_amdgcn_mfma_f32_16x16x32_bf16(ah[mi],  bl4[ni], acc[mi][ni], 0, 0, 0);
        acc[mi][ni] = __builtin_amdgcn_mfma_f32_16x16x32_bf16(al4[mi], bh[ni],  acc[mi][ni], 0, 0, 0);
      }
  }
#pragma unroll
  for (int mi = 0; mi < 2; ++mi)
#pragma unroll
  for (int ni = 0; ni < 2; ++ni)
#pragma unroll
  for (int r = 0; r < 4; ++r) {
    int m = m0 + wr * 32 + mi * 16 + ((l >> 4) << 2) + r;
    int n = n0 + wc * 32 + ni * 16 + (l & 15);
    bool rowK = (m >= k0 && m < k0 + 64);
    bool colK = (n >= k0 && n < k0 + 64);
    float v;
    if (rowK)      v = Rb[(long)(m - k0) * 1024 + n];
    else if (colK) v = -acc[mi][ni][r];
    else           v = Wb[(long)m * 1024 + n] - acc[mi][ni][r];
    Wb[(long)m * 1024 + n] = v;
    int cn = n - k0 - 64;
    if (cn >= 0 && cn < 64) {
      unsigned short h = bf16rne(v);
      float hf = __uint_as_float((unsigned)h << 16);
      CnH[(long)m * 64 + cn] = h;
      CnL[(long)m * 64 + cn] = bf16rne(v - hf);
    }
  }
}

// ---------------- d0, diag, df col 0 ----------------
__global__ void ddiag_k(const float* __restrict__ W, const float* __restrict__ fi,
                        float* __restrict__ d0, float* __restrict__ diag, float* __restrict__ dfout){
  int t = blockIdx.x * 256 + threadIdx.x;
  int b = t >> 10, i = t & 1023;
  const float* Wb = W + (long)b * TT * TT;
  float dv = fi[t] * Wb[(long)i * TT];
  d0[t] = dv;
  diag[t] = Wb[(long)i * TT + i];
  dfout[(long)b * TT * 1025 + (long)i * 1025] = dv;
}

// ---------------- dx: compute, emit bf16 dx + bf16 dx^T + df store ----------------
__global__ __launch_bounds__(256) void dx_k(const float* __restrict__ A, const float* __restrict__ W,
                                            const float* __restrict__ diag, float* __restrict__ dfout,
                                            unsigned short* __restrict__ dxb, unsigned short* __restrict__ dxTb){
  int b = blockIdx.z;
  int i0 = blockIdx.y * 64, j0 = blockIdx.x * 64;
  const float* Wb = W + (long)b * TT * TT;
  const float* Ab = A + (long)b * TT * TT;
  __shared__ float Ls[64][65];
  __shared__ float Sx[64][65];
  int tid = threadIdx.x;
  for (int idx = tid; idx < 4096; idx += 256) {
    int r = idx >> 6, c = idx & 63;
    Ls[r][c] = Wb[(long)(j0 + r) * TT + i0 + c];
  }
  __syncthreads();
  for (int idx = tid; idx < 4096; idx += 256) {
    int r = idx >> 6, c = idx & 63;
    int i = i0 + r, j = j0 + c;
    float a = Ab[(long)i * TT + j];
    float v = 0.f;
    if (j > 0) v = a * diag[b * TT + j];
    if (i > 0) v -= a * Ls[c][r];
    dxb[(long)b * 1048576 + (long)i * 1024 + j] = bf16rne(v);
    Sx[r][c] = v;
  }
  __syncthreads();
  float* dfb = dfout + (long)b * TT * 1025;
  unsigned short* dtb = dxTb + (long)b * 1048576;
  for (int idx = tid; idx < 4096; idx += 256) {
    int r = idx >> 6, c = idx & 63;
    float v = Sx[c][r];
    dfb[(long)(j0 + r) * 1025 + i0 + 1 + c] = v;
    dtb[(long)(j0 + r) * 1024 + i0 + c] = bf16rne(v);
  }
}

extern "C" void kernel_launch(void* const* d_in, const int* in_sizes, int n_in,
                              void* d_out, int out_size, void* d_ws, size_t ws_size,
                              hipStream_t stream){
  const float* input   = (const float*)d_in[0];
  const float* Wtp     = (const float*)d_in[1];
  const float* btp     = (const float*)d_in[2];
  const float* Wtc     = (const float*)d_in[3];
  const float* btc     = (const float*)d_in[4];
  const float* wfi     = (const float*)d_in[5];
  const float* Wbil    = (const float*)d_in[6];
  const float* exparam = (const float*)d_in[7];
  const float* Wfz     = (const float*)d_in[8];
  const float* bfz     = (const float*)d_in[9];

  if (ws_size < 147000000UL) return;

  float* ws   = (float*)d_ws;
  float* sem   = ws;                    // 4,194,304 f
  float* strv  = ws + 4194304;          // 4,194,304 f  [later: dxb bf16]
  float* Abuf  = ws + 8388608;          // 8,388,608 f  [later: finpb bf16]
  float* Wbuf  = ws + 16777216;         // 8,388,608 f
  unsigned short* strb = (unsigned short*)(ws + 25165824);
  unsigned short* tpb  = (unsigned short*)(ws + 27262976);
  unsigned short* tcb  = (unsigned short*)(ws + 29360128);
  unsigned short* tpwb = (unsigned short*)(ws + 31457280);
  unsigned short* wtpb = (unsigned short*)(ws + 33554432);
  unsigned short* wtcb = (unsigned short*)(ws + 33685504);
  unsigned short* wbilT= (unsigned short*)(ws + 33816576);
  unsigned short* wfzb = (unsigned short*)(ws + 33947648);
  float* fi    = ws + 34340864;         // 8192
  float* csp   = ws + 34349056;         // 131,072
  float* d0    = ws + 34480128;         // 8192
  float* dg    = ws + 34488320;         // 8192
  float* Rnew  = ws + 34496512;         // 524,288
  unsigned short* ChA = (unsigned short*)(ws + 35020800);
  unsigned short* ClA = (unsigned short*)(ws + 35282944);
  unsigned short* ChB = (unsigned short*)(ws + 35545088);
  unsigned short* ClB = (unsigned short*)(ws + 35807232);
  unsigned short* RTh = (unsigned short*)(ws + 36069376);
  unsigned short* RTl = (unsigned short*)(ws + 36331520);
  unsigned short* dxb   = (unsigned short*)strv;
  unsigned short* dxTb  = (unsigned short*)(ws + 25165824);
  unsigned short* semTb = (unsigned short*)(ws + 29360128);
  unsigned short* finpb = (unsigned short*)Abuf;

  float* outp = (float*)d_out;
  float* dfp  = outp + 4194304;

  split_k<<<8192, 256, 0, stream>>>(input, sem, strv, strb, wfi, fi);
  castmisc_k<<<1536, 256, 0, stream>>>(Wtp, Wtc, Wfz, Wbil, wtpb, wtcb, wfzb, wbilT);
  mgemm_k<1,1><<<dim3(4,128,1),256,0,stream>>>(strb, wtpb, tpb, 512, 512, 512, 512, 0,0,0, btp, nullptr,0,nullptr);
  mgemm_k<1,1><<<dim3(4,128,1),256,0,stream>>>(strb, wtcb, tcb, 512, 512, 512, 512, 0,0,0, btc, nullptr,0,nullptr);
  mgemm_k<0,1><<<dim3(4,128,1),256,0,stream>>>(tpb, wbilT, tpwb, 512, 512, 512, 512, 0,0,0, nullptr, nullptr,0,nullptr);
  mgemm_score_k<<<dim3(8,16,8),256,0,stream>>>(tpwb, tcb, Abuf, Wbuf, csp);
  castT_k<<<dim3(16,32,8), 256, 0, stream>>>(sem, semTb, 1024, 512, 524288, 524288);
  buildfix_k<<<dim3(16,8),256,0,stream>>>(csp, fi, Wbuf, ChA, ClA);
  for (int s = 0; s < 16; ++s) {
    int k0 = s * NB;
    unsigned short* ChI = (s & 1) ? ChB : ChA;
    unsigned short* ClI = (s & 1) ? ClB : ClA;
    unsigned short* ChO = (s & 1) ? ChA : ChB;
    unsigned short* ClO = (s & 1) ? ClA : ClB;
    gj_fprep2_k<<<dim3(8,16),256,0,stream>>>(Wbuf, Rnew, RTh, RTl, k0);
    gupd_k<<<dim3(8,16,16),256,0,stream>>>(ChI, ClI, RTh, RTl, Rnew, Wbuf, ChO, ClO, k0);
  }
  ddiag_k<<<32,256,0,stream>>>(Wbuf, fi, d0, dg, dfp);
  dx_k<<<dim3(16,16,8),256,0,stream>>>(Abuf, Wbuf, dg, dfp, dxb, dxTb);
  semcopy_k<<<4096,256,0,stream>>>(sem, finpb);
  mgemm_pc_k<<<dim3(4,16,16),256,0,stream>>>(dxTb, dxb, semTb, finpb + 512, finpb + 1024,
                                             1024, 1024, 1024, 1536, 1048576, 524288, 1572864,
                                             d0, 1024, exparam);
  mgemm_k<3,0><<<dim3(4,128,1),256,0,stream>>>(finpb, wfzb, outp, 1536, 1536, 1536, 512, 0,0,0, bfz, nullptr,0,nullptr);
}